// Round 7
// baseline (501.372 us; speedup 1.0000x reference)
//
#include <hip/hip_runtime.h>
#include <hip/hip_bf16.h>
#include <math.h>

// ---------------------------------------------------------------------------
// DIM=256 HEADS=16 DHEAD=16 H=12 W=26 (HW=312)  Hk=3 Wk=6 (J=18)  B=256
// q_map[b,c,s] = q[b,(c*56+s)&255]
// Round 14: 2-launch split. Evidence r12 vs r13 (same 63KB LDS):
//   VGPR 64 -> 45.8% occ (2 blocks/CU);  VGPR 100 -> 21.9% (1 block/CU).
// Co-residency gate is the VGPR slot. r12 spilled because demand ~100 at a
// 64 target; this round makes demand GENUINELY <= 64:
//   - W2/W3 MFMA fragments -> per-lane LDS tables (8.7KB + 2.5KB)
//   - Bk fragments rebuilt per chunk from k LDS copy (10KB); syncthreads
//     stops hoisting, so they never stay live across the loop
//   - h2w transpose buffer aliases the DEAD Sp half of the S double buffer
//     (phase (b) only; Sp consumed in phase (a)) -> LDS ~65KB, 2 blocks fit
//   - wAcc[9] half-split softmax (r12 form)
// Launch count 3->2: tail folded into k_chunks via threadfence+atomicAdd
// (last of the 2 blocks per b does m/pooled/LN; cnt zeroed by k_setup).
// Bench arithmetic: overhead ~118us + ~18us/extra launch; 3-launch ties 261
// at best, 2-launch with co-resident chunks -> ~245.
// ---------------------------------------------------------------------------

typedef __attribute__((ext_vector_type(8))) short short8;   // 8 bf16
typedef __attribute__((ext_vector_type(4))) float floatx4;

union U16 { uint4 u; short8 s; };

#define MFMA(A, B, C) __builtin_amdgcn_mfma_f32_16x16x32_bf16((A), (B), (C), 0, 0, 0)

__device__ __forceinline__ unsigned int f2bf(float f) {   // RNE f32->bf16 (low 16)
    unsigned int u = __float_as_uint(f);
    u += 0x7fffu + ((u >> 16) & 1u);
    return u >> 16;
}
__device__ __forceinline__ unsigned int pk2(float a, float b) {   // HW cvt_pk
    __hip_bfloat162 h = __float22bfloat162_rn(make_float2(a, b));
    union { __hip_bfloat162 h; unsigned int u; } cv; cv.h = h;
    return cv.u;
}
__device__ __forceinline__ float bf2f(unsigned short v) {
    return __uint_as_float((unsigned int)v << 16);
}
__device__ __forceinline__ uint4 pack8(float4 a, float4 b) {
    uint4 r;
    r.x = pk2(a.x, a.y); r.y = pk2(a.z, a.w);
    r.z = pk2(b.x, b.y); r.w = pk2(b.z, b.w);
    return r;
}

// ===========================================================================
// Kernel 1: setup (r7-verbatim phases) + export; zeroes the tail counter
// ===========================================================================
__global__ __launch_bounds__(512, 2) void k_setup(
    const float* __restrict__ x, const float* __restrict__ q,
    const float* __restrict__ w_dw, const float* __restrict__ b_dw,
    const float* __restrict__ w_pw,
    const float* __restrict__ wk, const float* __restrict__ wv,
    unsigned short* __restrict__ ws_q, unsigned short* __restrict__ ws_k,
    unsigned short* __restrict__ ws_v, float* __restrict__ ws_n01,
    unsigned int* __restrict__ ws_cnt)
{
    const int b = blockIdx.x, tid = threadIdx.x;
    const int w = tid >> 6, lane = tid & 63;
    const int n = lane & 15, qd = lane >> 4;

    __shared__ unsigned short q_sb[256];
    __shared__ unsigned short v_sb[5120];           // [256][20]
    __shared__ float off_s[36], n0_s[18], n1_s[18];
    __shared__ float sx0[18], sy0[18], swx[18], swy[18];
    __shared__ __align__(16) unsigned char UB[34944];
    float* qsw = (float*)UB;                         // 4128 f (16 x 258)
    unsigned short* kvT = (unsigned short*)UB;       // [18][264] aliases qsw
    float* t_s = (float*)(UB + 16512);               // [18][256]
    unsigned short* k_sb = (unsigned short*)(UB + 16512);  // [256][20] aliases t_s

    if (tid == 0) ws_cnt[b] = 0u;

    // ---- stage 0 ----
    if (tid < 256) {
        const float qv = q[b * 256 + tid];
        const unsigned short qb = (unsigned short)f2bf(qv * 0.25f);
        q_sb[tid] = qb;
        ws_q[b * 256 + tid] = qb;
    }
    for (int u = tid; u < 4128; u += 512) {
        const int r = u / 258, i = u - r * 258;
        qsw[u] = (i < 256) ? q[b * 256 + i] : 0.f;
    }
    __syncthreads();

    // ---- depthwise conv 6x6 s4 p1 + GELU -> t_s ----
    {
        const int c = tid & 255, g = tid >> 8;     // g: jw-half
        float wreg[36];
        const float4* wdw4 = (const float4*)w_dw;  // [c][36] contiguous
        #pragma unroll
        for (int i = 0; i < 9; ++i) {
            const float4 t4 = wdw4[c * 9 + i];
            wreg[i * 4 + 0] = t4.x; wreg[i * 4 + 1] = t4.y;
            wreg[i * 4 + 2] = t4.z; wreg[i * 4 + 3] = t4.w;
        }
        float acc[9];
        const float bv = b_dw[c];
        #pragma unroll
        for (int a = 0; a < 9; ++a) acc[a] = bv;
        const int cb = (c * 56) & 255;
        const int cp = (c & 15) * 258;
        for (int jh = 0; jh < 3; ++jh) {
            for (int kh = 0; kh < 6; ++kh) {
                const int ih = jh * 4 - 1 + kh;
                if (ih < 0 || ih >= 12) continue;
                const int rb = ih * 26;
                #pragma unroll
                for (int jwl = 0; jwl < 3; ++jwl) {
                    const int jw = g * 3 + jwl;
                    #pragma unroll
                    for (int kw = 0; kw < 6; ++kw) {
                        const int iw = jw * 4 - 1 + kw;
                        if (iw < 0 || iw >= 26) continue;
                        acc[jh * 3 + jwl] += wreg[kh * 6 + kw] * qsw[cp + ((cb + rb + iw) & 255)];
                    }
                }
            }
        }
        #pragma unroll
        for (int a = 0; a < 9; ++a) {
            const int jh = a / 3, jwl = a - jh * 3;
            const int p = jh * 6 + g * 3 + jwl;
            const float v = acc[a];
            t_s[p * 256 + c] = 0.5f * v * (1.0f + erff(v * 0.70710678118654752f));
        }
    }
    __syncthreads();

    // ---- offsets: 36 dots over 256 channels ----
    for (int oi = w; oi < 36; oi += 8) {
        const int o = oi / 18, p = oi - o * 18;
        float s = 0.f;
        for (int c = lane; c < 256; c += 64) s += w_pw[o * 256 + c] * t_s[p * 256 + c];
        for (int d = 32; d > 0; d >>= 1) s += __shfl_down(s, d, 64);
        if (lane == 0) off_s[oi] = 4.0f * tanhf(s);
    }
    __syncthreads();

    // ---- grid coords + bilinear params (+ n0/n1 export) ----
    if (tid < 18) {
        const int j = tid, jh = j / 6, jw = j - jh * 6;
        const float vg0 = (float)jw + off_s[j];
        const float vg1 = (float)jh + off_s[18 + j];
        const float n0 = 2.0f * vg0 / 2.0f - 1.0f;
        const float n1 = 2.0f * vg1 / 5.0f - 1.0f;
        n0_s[j] = n0; n1_s[j] = n1;
        ws_n01[b * 36 + j] = n0;
        ws_n01[b * 36 + 18 + j] = n1;
        const float xp = ((n0 + 1.0f) * 26.0f - 1.0f) * 0.5f;
        const float yp = ((n1 + 1.0f) * 12.0f - 1.0f) * 0.5f;
        const float x0 = floorf(xp), y0 = floorf(yp);
        sx0[j] = x0; sy0[j] = y0; swx[j] = xp - x0; swy[j] = yp - y0;
    }
    __syncthreads();

    // ---- bilinear sample -> kvT bf16 [j][264] (qsw region dead) ----
    {
        const int c = tid & 255, g = tid >> 8;
        const float* xb = x + ((size_t)b * 256 + c) * 312;
        for (int jj = 0; jj < 9; ++jj) {
            const int j = g * 9 + jj;
            const int x0 = (int)sx0[j], y0 = (int)sy0[j];
            const int x1 = x0 + 1, y1 = y0 + 1;
            const float wx1 = swx[j], wy1 = swy[j];
            const float wx0 = 1.f - wx1, wy0 = 1.f - wy1;
            const bool xv0 = (x0 >= 0) & (x0 < 26), xv1 = (x1 >= 0) & (x1 < 26);
            const bool yv0 = (y0 >= 0) & (y0 < 12), yv1 = (y1 >= 0) & (y1 < 12);
            const float v00 = (xv0 & yv0) ? xb[y0 * 26 + x0] : 0.f;
            const float v01 = (xv1 & yv0) ? xb[y0 * 26 + x1] : 0.f;
            const float v10 = (xv0 & yv1) ? xb[y1 * 26 + x0] : 0.f;
            const float v11 = (xv1 & yv1) ? xb[y1 * 26 + x1] : 0.f;
            const float val = wy0 * (wx0 * v00 + wx1 * v01) + wy1 * (wx0 * v10 + wx1 * v11);
            kvT[j * 264 + c] = (unsigned short)f2bf(val);
        }
    }
    __syncthreads();

    // ---- k/v projection via MFMA: wave w -> matrix (w&1), mtb = w>>1 ----
    {
        const int m2 = w & 1, mtb = w >> 1;
        const float4* wm4 = (const float4*)(m2 ? wv : wk);
        floatx4 pa[4][2];
        #pragma unroll
        for (int a = 0; a < 4; ++a) {
            pa[a][0] = (floatx4){0.f, 0.f, 0.f, 0.f};
            pa[a][1] = (floatx4){0.f, 0.f, 0.f, 0.f};
        }
        #pragma unroll 2
        for (int ks = 0; ks < 8; ++ks) {
            U16 b0, b1;
            b0.u = *(const uint4*)(kvT + n * 264 + ks * 32 + qd * 8);
            b1.u = make_uint4(0u, 0u, 0u, 0u);
            if (n < 2) b1.u = *(const uint4*)(kvT + (16 + n) * 264 + ks * 32 + qd * 8);
            #pragma unroll
            for (int mtl = 0; mtl < 4; ++mtl) {
                const int mt = mtb + mtl * 4;
                const int f4i = (mt * 16 + n) * 64 + ks * 8 + qd * 2;
                U16 A; A.u = pack8(wm4[f4i], wm4[f4i + 1]);
                pa[mtl][0] = MFMA(A.s, b0.s, pa[mtl][0]);
                pa[mtl][1] = MFMA(A.s, b1.s, pa[mtl][1]);
            }
        }
        unsigned short* dst = m2 ? v_sb : k_sb;
        #pragma unroll
        for (int mtl = 0; mtl < 4; ++mtl) {
            const int mt = mtb + mtl * 4;
            #pragma unroll
            for (int r = 0; r < 4; ++r) {
                const int o = mt * 16 + qd * 4 + r;
                dst[o * 20 + n] = (unsigned short)f2bf(pa[mtl][0][r]);
                if (n < 2) dst[o * 20 + 16 + n] = (unsigned short)f2bf(pa[mtl][1][r]);
            }
        }
    }
    __syncthreads();

    // ---- export k padded [256][20], v compact [256][18] ----
    for (int u = tid; u < 5120; u += 512) ws_k[b * 5120 + u] = k_sb[u];
    for (int u = tid; u < 4608; u += 512) {
        const int c = u / 18, j = u - c * 18;
        ws_v[b * 4608 + u] = v_sb[c * 20 + j];
    }
}

// ===========================================================================
// Kernel 2: chunk loop + folded tail. Block (b,g): i in [g*156, +156).
// Genuine <=64-reg body: all persistent fragments live in LDS.
// ===========================================================================
__global__ __launch_bounds__(512, 4) void k_chunks(
    const float* __restrict__ cw1, const float* __restrict__ cb1,
    const float* __restrict__ cw2, const float* __restrict__ cb2,
    const float* __restrict__ cw3, const float* __restrict__ cb3,
    const float* __restrict__ conv_w, const float* __restrict__ conv_b,
    const float* __restrict__ q, const float* __restrict__ w_out,
    const float* __restrict__ b_out,
    const float* __restrict__ ln_g, const float* __restrict__ ln_b,
    const unsigned short* __restrict__ ws_q, const unsigned short* __restrict__ ws_k,
    const unsigned short* __restrict__ ws_v, const float* __restrict__ ws_n01,
    float* __restrict__ ws_wa, unsigned int* __restrict__ ws_cnt,
    float* __restrict__ out)
{
    const int bb = blockIdx.x;                     // 0..511
    const int b = bb >> 1, g = bb & 1;
    const int tid = threadIdx.x;
    const int w = tid >> 6, lane = tid & 63;       // w in 0..7
    const int n = lane & 15, qd = lane >> 4;

    __shared__ unsigned short q_sb[256];
    __shared__ unsigned short k_sb2[5120];          // [256][20]
    __shared__ float F0[468], F1[216];
    __shared__ float n0_s[18], n1_s[18];
    __shared__ unsigned int lutxy[312];
    __shared__ float b2_s[64], b3_s[16];
    __shared__ __align__(16) float w1p[4][8][8];
    __shared__ __align__(16) unsigned int w2f_l[64 * 34];   // per-lane W2 frags
    __shared__ __align__(16) unsigned int w3f_l[64 * 10];   // per-lane W3 frags
    __shared__ int lastf;
    // S double buffer 2 x [16 il][18 j][17 h] f32 = 39168 B.
    // h2w (mlp transpose) aliases the DEAD Sp half each chunk.
    __shared__ __align__(16) unsigned char UB[39168];
    float* Sbuf = (float*)UB;
    float* wred = (float*)UB;                      // 512*9*4 = 18432 < 19584

    // ---- table loads ----
    if (tid < 256) q_sb[tid] = ws_q[b * 256 + tid];
    {
        const unsigned int* src = (const unsigned int*)(ws_k + b * 5120);
        unsigned int* dst = (unsigned int*)k_sb2;
        for (int u = tid; u < 2560; u += 512) dst[u] = src[u];
    }
    if (tid < 36) {
        if (tid < 18) n0_s[tid] = ws_n01[b * 36 + tid];
        else          n1_s[tid - 18] = ws_n01[b * 36 + tid];
    }
    if (tid < 312) {
        const int iy = tid / 26;
        lutxy[tid] = (unsigned int)(tid - iy * 26) | ((unsigned int)iy << 16);
    }
    if (tid < 64) b2_s[tid] = cb2[tid];
    if (tid < 16) b3_s[tid] = cb3[tid];
    if (tid >= 128 && tid < 160) {                 // CPB layer-1 weight table
        const int t2 = tid - 128;
        const int qdi = t2 >> 3, kp = t2 & 7;
        const int kk0 = 2 * kp, kk1 = 2 * kp + 1;
        const int kid0 = (kk0 < 8) ? (qdi * 8 + kk0) : (32 + qdi * 8 + kk0 - 8);
        const int kid1 = (kk1 < 8) ? (qdi * 8 + kk1) : (32 + qdi * 8 + kk1 - 8);
        w1p[qdi][kp][0] = cw1[kid0 * 2];
        w1p[qdi][kp][1] = cw1[kid0 * 2 + 1];
        w1p[qdi][kp][2] = cb1[kid0];
        w1p[qdi][kp][3] = cw1[kid1 * 2];
        w1p[qdi][kp][4] = cw1[kid1 * 2 + 1];
        w1p[qdi][kp][5] = cb1[kid1];
    }
    if (tid < 64) {                                // per-lane W2 fragments
        const float4* cw2_4 = (const float4*)cw2;
        const int nl = tid & 15, ql = tid >> 4;
        #pragma unroll
        for (int mtl = 0; mtl < 4; ++mtl)
            #pragma unroll
            for (int ks = 0; ks < 2; ++ks) {
                const int base = (mtl * 16 + nl) * 16 + ks * 8 + ql * 2;
                const uint4 v = pack8(cw2_4[base], cw2_4[base + 1]);
                unsigned int* p = &w2f_l[tid * 34 + (mtl * 2 + ks) * 4];
                p[0] = v.x; p[1] = v.y; p[2] = v.z; p[3] = v.w;
            }
    } else if (tid < 128) {                        // per-lane W3 fragments
        const int l = tid - 64;
        const float4* cw3_4 = (const float4*)cw3;
        const int nl = l & 15, ql = l >> 4;
        #pragma unroll
        for (int ks = 0; ks < 2; ++ks) {
            const int base = nl * 16 + ks * 8 + ql * 2;
            const uint4 v = pack8(cw3_4[base], cw3_4[base + 1]);
            unsigned int* p = &w3f_l[l * 10 + ks * 4];
            p[0] = v.x; p[1] = v.y; p[2] = v.z; p[3] = v.w;
        }
    }
    __syncthreads();

    // ---- F0/F1 log tables (from n0/n1) ----
    for (int u = tid; u < 684; u += 512) {
        if (u < 468) {
            const int ixv = u / 18, j = u - ixv * 18;
            const float p0 = (float)ixv * (2.0f / 11.0f) - 1.0f - n0_s[j];
            F0[u] = copysignf(__logf(1.0f + fabsf(p0)), p0);
        } else {
            const int u2 = u - 468;
            const int iyv = u2 / 18, j = u2 - iyv * 18;
            const float p1 = (float)iyv * (2.0f / 25.0f) - 1.0f - n1_s[j];
            F1[u2] = copysignf(__logf(1.0f + fabsf(p1)), p1);
        }
    }
    __syncthreads();

    // ---- pipelined chunk loop: 10 chunks of 16 i's (last 12) ----
    float wAcc[9];
    #pragma unroll
    for (int jl = 0; jl < 9; ++jl) wAcc[jl] = 0.f;

    auto soft_acc = [&](int chp, const float* Sp) {
        const int h = tid & 15, hf = (tid >> 4) & 1, il = tid >> 5;   // il 0..15
        const int CIp = (chp == 9) ? 12 : 16;
        if (il < CIp) {                                   // wave-uniform
            const float cwv = conv_w[g * 156 + chp * 16 + il];
            float lv[9];
            const float* row = Sp + (il * 18 + hf * 9) * 17 + h;
            #pragma unroll
            for (int jl = 0; jl < 9; ++jl) lv[jl] = row[jl * 17];
            float m = lv[0];
            #pragma unroll
            for (int jl = 1; jl < 9; ++jl) m = fmaxf(m, lv[jl]);
            m = fmaxf(m, __shfl_xor(m, 16, 64));
            float s = 0.f;
            #pragma unroll
            for (int jl = 0; jl < 9; ++jl) { lv[jl] = __expf(lv[jl] - m); s += lv[jl]; }
            s += __shfl_xor(s, 16, 64);
            const float wgt = cwv / s;
            #pragma unroll
            for (int jl = 0; jl < 9; ++jl) wAcc[jl] = fmaf(wgt, lv[jl], wAcc[jl]);
        }
    };

    for (int ch = 0; ch < 10; ++ch) {
        float* Sc = Sbuf + (ch & 1) * 4896;
        float* SpF = Sbuf + ((ch & 1) ^ 1) * 4896;
        unsigned int* h2w = (unsigned int*)SpF;    // phase-(b) alias of dead Sp
        const int ibase = g * 156 + ch * 16;

        // (a) sim: wave w -> heads 2w, 2w+1; Bk rebuilt from k_sb2 (LDS)
        #pragma unroll 1
        for (int hh = 0; hh < 2; ++hh) {
            const int h = w * 2 + hh;
            const int base = h * 16 + qd * 8;
            uint4 Bk[2];
            #pragma unroll
            for (int jt = 0; jt < 2; ++jt) {
                unsigned int u0 = 0, u1 = 0, u2 = 0, u3 = 0;
                if (qd < 2 && (jt == 0 || n < 2)) {
                    const int j = jt * 16 + n;
                    const int cb0 = base * 20 + j;
                    u0 = (unsigned)k_sb2[cb0] | ((unsigned)k_sb2[cb0 + 20] << 16);
                    u1 = (unsigned)k_sb2[cb0 + 40] | ((unsigned)k_sb2[cb0 + 60] << 16);
                    u2 = (unsigned)k_sb2[cb0 + 80] | ((unsigned)k_sb2[cb0 + 100] << 16);
                    u3 = (unsigned)k_sb2[cb0 + 120] | ((unsigned)k_sb2[cb0 + 140] << 16);
                }
                Bk[jt] = make_uint4(u0, u1, u2, u3);
            }
            unsigned int a0 = 0, a1 = 0, a2 = 0, a3u = 0;
            if (qd < 2) {
                const int ii = ibase + n;
                a0 = (unsigned)q_sb[((base + 0) * 56 + ii) & 255] |
                     ((unsigned)q_sb[((base + 1) * 56 + ii) & 255] << 16);
                a1 = (unsigned)q_sb[((base + 2) * 56 + ii) & 255] |
                     ((unsigned)q_sb[((base + 3) * 56 + ii) & 255] << 16);
                a2 = (unsigned)q_sb[((base + 4) * 56 + ii) & 255] |
                     ((unsigned)q_sb[((base + 5) * 56 + ii) & 255] << 16);
                a3u = (unsigned)q_sb[((base + 6) * 56 + ii) & 255] |
                      ((unsigned)q_sb[((base + 7) * 56 + ii) & 255] << 16);
            }
            U16 Af; Af.u = make_uint4(a0, a1, a2, a3u);
            #pragma unroll
            for (int jt = 0; jt < 2; ++jt) {
                U16 Bf; Bf.u = Bk[jt];
                floatx4 D = {0.f, 0.f, 0.f, 0.f};
                D = MFMA(Af.s, Bf.s, D);
                const int j = jt * 16 + n;
                if (j < 18) {
                    #pragma unroll
                    for (int r = 0; r < 4; ++r)
                        Sc[((qd * 4 + r) * 18 + j) * 17 + h] = D[r];
                }
            }
        }
        // (c of ch-1) overlapped with (a): reads SpF before h2w trashes it
        if (ch > 0) soft_acc(ch - 1, SpF);
        __syncthreads();

        // (b) CPB MLP + logits; 18 tiles over 8 waves; h2w in dead Sp
        {
            auto mlp1 = [&](int j) {
                const int i0 = ibase + n;
                const unsigned int lv2 = lutxy[(i0 < 312) ? i0 : 311];
                const int ix = (int)(lv2 & 0xffffu), iy = (int)(lv2 >> 16);
                const float f0 = F0[ix * 18 + j];
                const float f1 = F1[iy * 18 + j];
                U16 ub0, ub1;
                {
                    unsigned int uu[8];
                    #pragma unroll
                    for (int kp = 0; kp < 8; ++kp) {
                        const float* wp = &w1p[qd][kp][0];
                        const float ha = fmaxf(fmaf(wp[0], f0, fmaf(wp[1], f1, wp[2])), 0.f);
                        const float hb = fmaxf(fmaf(wp[3], f0, fmaf(wp[4], f1, wp[5])), 0.f);
                        uu[kp] = pk2(ha, hb);
                    }
                    ub0.u = make_uint4(uu[0], uu[1], uu[2], uu[3]);
                    ub1.u = make_uint4(uu[4], uu[5], uu[6], uu[7]);
                }
                // GEMM2 -> h2 to this wave's region (W2 frags from LDS)
                unsigned int* hw = h2w + w * 544 + n * 34;
                #pragma unroll
                for (int mtl = 0; mtl < 4; ++mtl) {
                    U16 A0, A1;
                    A0.u = *(const uint4*)&w2f_l[lane * 34 + (mtl * 2) * 4];
                    A1.u = *(const uint4*)&w2f_l[lane * 34 + (mtl * 2 + 1) * 4];
                    floatx4 acc = {0.f, 0.f, 0.f, 0.f};
                    acc = MFMA(A0.s, ub0.s, acc);
                    acc = MFMA(A1.s, ub1.s, acc);
                    const float e0 = fmaxf(acc[0] + b2_s[mtl*16 + qd*4 + 0], 0.f);
                    const float e1 = fmaxf(acc[1] + b2_s[mtl*16 + qd*4 + 1], 0.f);
                    const float e2 = fmaxf(acc[2] + b2_s[mtl*16 + qd*4 + 2], 0.f);
                    const float e3 = fmaxf(acc[3] + b2_s[mtl*16 + qd*4 + 3], 0.f);
                    hw[mtl * 8 + qd * 2]     = pk2(e0, e1);
                    hw[mtl * 8 + qd * 2 + 1] = pk2(e2, e3);
                }
                // GEMM3 (W3 frags from LDS; wave-local lgkm drain)
                const unsigned int* hwr = h2w + w * 544;
                U16 uc0, uc1;
                uc0.u = *(const uint4*)(hwr + n * 34 + qd * 4);
                uc1.u = *(const uint4*)(hwr + n * 34 + 16 + qd * 4);
                U16 A0, A1;
                A0.u = *(const uint4*)&w3f_l[lane * 10];
                A1.u = *(const uint4*)&w3f_l[lane * 10 + 4];
                floatx4 a3 = {0.f, 0.f, 0.f, 0.f};
                a3 = MFMA(A0.s, uc0.s, a3);
                a3 = MFMA(A1.s, uc1.s, a3);
                float* sp = Sc + (n * 18 + j) * 17 + qd * 4;
                #pragma unroll
                for (int r = 0; r < 4; ++r) sp[r] = a3[r] + b3_s[qd * 4 + r] + sp[r];
            };
            mlp1(w);
            mlp1(w + 8);
            if (w < 2) mlp1(16 + w);
        }
        __syncthreads();
    }
    // drain: softmax for final chunk (buffer 9&1 = 1)
    soft_acc(9, Sbuf + 4896);

    // ---- reduce wAcc over 16 il-slots -> ws_wa[(b,g)][288] ----
    #pragma unroll
    for (int jl = 0; jl < 9; ++jl) wred[tid * 9 + jl] = wAcc[jl];
    __syncthreads();
    if (tid < 288) {
        const int h = tid / 18, j2 = tid - h * 18;
        const int hf = (j2 >= 9) ? 1 : 0, jl = j2 - hf * 9;
        float s = 0.f;
        #pragma unroll
        for (int sl = 0; sl < 16; ++sl) s += wred[(sl * 32 + hf * 16 + h) * 9 + jl];
        ws_wa[(b * 2 + g) * 288 + tid] = s;
    }
    // ---- last-block-done gate (split-K completion idiom) ----
    __threadfence();
    __syncthreads();
    if (tid == 0) {
        const unsigned int old = atomicAdd(&ws_cnt[b], 1u);
        lastf = (old == 1) ? 1 : 0;
    }
    __syncthreads();
    if (!lastf) return;
    __threadfence();   // acquire side: invalidate L1 before reading peer data

    // ---- folded tail: m, pooled, residual + LayerNorm ----
    float* TB = Sbuf + 4896;           // buffer-1 region, dead after soft_acc(9)
    float* wA_s = TB;                  // 288
    float* m_s = TB + 288;             // 256, 16B-aligned
    float* pooled_s = TB + 544;        // 256
    float* redb = TB + 800;            // 24

    for (int u = tid; u < 288; u += 512)
        wA_s[u] = ws_wa[(b * 2) * 288 + u] + ws_wa[(b * 2 + 1) * 288 + u];
    {
        float v = (tid < 312) ? conv_w[tid] : 0.f;
        for (int d = 32; d > 0; d >>= 1) v += __shfl_down(v, d, 64);
        if (lane == 0) redb[16 + w] = v;
    }
    __syncthreads();

    if (tid < 256) {
        const int hb = (tid >> 4) * 18;
        const unsigned short* vb = ws_v + b * 4608 + tid * 18;
        float acc = 0.f;
        #pragma unroll
        for (int j = 0; j < 18; ++j) acc += wA_s[hb + j] * bf2f(vb[j]);
        m_s[tid] = acc;
    }
    __syncthreads();

    float Ssum = 0.f;
    #pragma unroll
    for (int i = 0; i < 8; ++i) Ssum += redb[16 + i];

    // pooled = w_out . m  (8 waves x 32 rows, coalesced float4)
    {
        const float4 mm = *(const float4*)(m_s + lane * 4);
        for (int ol = 0; ol < 32; ++ol) {
            const int o = w * 32 + ol;
            const float4 wq = *(const float4*)(w_out + o * 256 + lane * 4);
            float d = wq.x * mm.x + wq.y * mm.y + wq.z * mm.z + wq.w * mm.w;
            for (int dd = 32; dd > 0; dd >>= 1) d += __shfl_down(d, dd, 64);
            if (lane == 0) pooled_s[o] = d;
        }
    }
    __syncthreads();

    if (tid < 256) {
        const float y = pooled_s[tid] + b_out[tid] * Ssum + conv_b[0] + q[b * 256 + tid];
        float s1 = y, s2 = y * y;
        for (int d = 32; d > 0; d >>= 1) { s1 += __shfl_down(s1, d, 64); s2 += __shfl_down(s2, d, 64); }
        if (lane == 0) { redb[w] = s1; redb[8 + w] = s2; }
    }
    __syncthreads();
    if (tid < 256) {
        const float y = pooled_s[tid] + b_out[tid] * Ssum + conv_b[0] + q[b * 256 + tid];
        const float S1 = redb[0] + redb[1] + redb[2] + redb[3];
        const float S2 = redb[8] + redb[9] + redb[10] + redb[11];
        const float mu = S1 * (1.0f / 256.0f);
        const float var = S2 * (1.0f / 256.0f) - mu * mu;
        out[b * 256 + tid] = (y - mu) * rsqrtf(var + 1e-5f) * ln_g[tid] + ln_b[tid];
    }
}

// ===========================================================================
extern "C" void kernel_launch(void* const* d_in, const int* in_sizes, int n_in,
                              void* d_out, int out_size, void* d_ws, size_t ws_size,
                              hipStream_t stream) {
    const float* x       = (const float*)d_in[0];
    const float* q       = (const float*)d_in[1];
    const float* w_dw    = (const float*)d_in[2];
    const float* b_dwp   = (const float*)d_in[3];
    const float* w_pw    = (const float*)d_in[4];
    const float* wk      = (const float*)d_in[5];
    const float* wv      = (const float*)d_in[6];
    const float* w_out   = (const float*)d_in[7];
    const float* b_out   = (const float*)d_in[8];
    const float* cw1     = (const float*)d_in[9];
    const float* cb1     = (const float*)d_in[10];
    const float* cw2     = (const float*)d_in[11];
    const float* cb2     = (const float*)d_in[12];
    const float* cw3     = (const float*)d_in[13];
    const float* cb3     = (const float*)d_in[14];
    const float* conv_w  = (const float*)d_in[15];
    const float* conv_b  = (const float*)d_in[16];
    const float* ln_g    = (const float*)d_in[17];
    const float* ln_b    = (const float*)d_in[18];
    float* out = (float*)d_out;

    // workspace layout (5,739,520 B total)
    char* wsb = (char*)d_ws;
    unsigned short* ws_q   = (unsigned short*)(wsb);                  // 131072
    unsigned short* ws_k   = (unsigned short*)(wsb + 131072);         // 2621440
    unsigned short* ws_v   = (unsigned short*)(wsb + 2752512);        // 2359296
    float*          ws_n01 = (float*)(wsb + 5111808);                 // 36864
    float*          ws_wa  = (float*)(wsb + 5148672);                 // 589824
    unsigned int*   ws_cnt = (unsigned int*)(wsb + 5738496);          // 1024

    k_setup<<<256, 512, 0, stream>>>(x, q, w_dw, b_dwp, w_pw, wk, wv,
                                     ws_q, ws_k, ws_v, ws_n01, ws_cnt);
    k_chunks<<<512, 512, 0, stream>>>(cw1, cb1, cw2, cb2, cw3, cb3,
                                      conv_w, conv_b, q, w_out, b_out,
                                      ln_g, ln_b,
                                      ws_q, ws_k, ws_v, ws_n01,
                                      ws_wa, ws_cnt, out);
}

// Round 8
// 259.128 us; speedup vs baseline: 1.9348x; 1.9348x over previous
//
#include <hip/hip_runtime.h>
#include <hip/hip_bf16.h>
#include <math.h>

// ---------------------------------------------------------------------------
// DIM=256 HEADS=16 DHEAD=16 H=12 W=26 (HW=312)  Hk=3 Wk=6 (J=18)  B=256
// q_map[b,c,s] = q[b,(c*56+s)&255]
// Round 15: monolithic r7 base + 3-buffer single-barrier chunk pipeline.
// Occupancy post-mortem (r9-r14): >512thr -> allocator shrinks regs+spill;
// 512thr cap<=64 -> spill (true demand >64 even with all weights in LDS);
// 512thr ~100-120 regs -> clean but HW gives 1 block/CU regardless (r13).
// So: keep r7's proven shape (512 thr, LB(512,2), ~120 regs, 1 block/CU)
// and cut the serial path instead:
//  - 3 S buffers (3x38.3KB): interval t runs sim(t)->S[t%3],
//    mlp(t-1) RMW S[(t-1)%3], soft(t-2) reads S[(t-2)%3] -- pairwise
//    distinct -> ONE barrier/interval: 12 barriers vs r7's 20, and each
//    interval has 3 phases of independent ILP to hide lgkm drains + exp.
//  - h2w 1 region/wave (17KB, sequential mlp1) to fit LDS (~152KB total)
//  - w1p CPB layer-1 weights in LDS (verified r10+); W2f/W3f/BkU in regs
// ---------------------------------------------------------------------------

typedef __attribute__((ext_vector_type(8))) short short8;   // 8 bf16
typedef __attribute__((ext_vector_type(4))) float floatx4;

union U16 { uint4 u; short8 s; };

#define MFMA(A, B, C) __builtin_amdgcn_mfma_f32_16x16x32_bf16((A), (B), (C), 0, 0, 0)

__device__ __forceinline__ unsigned int f2bf(float f) {   // RNE f32->bf16 (low 16)
    unsigned int u = __float_as_uint(f);
    u += 0x7fffu + ((u >> 16) & 1u);
    return u >> 16;
}
__device__ __forceinline__ unsigned int pk2(float a, float b) {   // HW cvt_pk
    __hip_bfloat162 h = __float22bfloat162_rn(make_float2(a, b));
    union { __hip_bfloat162 h; unsigned int u; } cv; cv.h = h;
    return cv.u;
}
__device__ __forceinline__ float bf2f(unsigned short v) {
    return __uint_as_float((unsigned int)v << 16);
}
__device__ __forceinline__ uint4 pack8(float4 a, float4 b) {
    uint4 r;
    r.x = pk2(a.x, a.y); r.y = pk2(a.z, a.w);
    r.z = pk2(b.x, b.y); r.w = pk2(b.z, b.w);
    return r;
}

// ===========================================================================
__global__ __launch_bounds__(512, 2) void k_all(
    const float* __restrict__ x, const float* __restrict__ q,
    const float* __restrict__ w_dw, const float* __restrict__ b_dw,
    const float* __restrict__ w_pw,
    const float* __restrict__ wk, const float* __restrict__ wv,
    const float* __restrict__ w_out, const float* __restrict__ b_out,
    const float* __restrict__ cw1, const float* __restrict__ cb1,
    const float* __restrict__ cw2, const float* __restrict__ cb2,
    const float* __restrict__ cw3, const float* __restrict__ cb3,
    const float* __restrict__ conv_w, const float* __restrict__ conv_b,
    const float* __restrict__ ln_g, const float* __restrict__ ln_b,
    float* __restrict__ out)
{
    const int b = blockIdx.x, tid = threadIdx.x;
    const int w = tid >> 6, lane = tid & 63;
    const int n = lane & 15, qd = lane >> 4;

    // ---- persistent LDS (~20.5 KB) ----
    __shared__ float qf_s[256];
    __shared__ unsigned short q_sb[256];            // bf16(q*0.25)
    __shared__ unsigned short v_sb[5120];           // v bf16 [256][20]
    __shared__ float F0[468], F1[216];              // log tables [26][18], [12][18]
    __shared__ unsigned int lutxy[312];             // ix | iy<<16
    __shared__ float off_s[36], n0_s[18], n1_s[18];
    __shared__ float sx0[18], sy0[18], swx[18], swy[18];
    __shared__ float b2_s[64], b3_s[16];
    __shared__ __align__(16) float w1p[4][8][8];    // [qd][kp][6 used]
    __shared__ float wA_s[288];
    __shared__ __align__(16) float m_s[256];
    __shared__ float pooled_s[256], redb[24];
    // ---- union region (134912 B) ----
    //   [0      .. 117504): S triple buffer, 3 x [32 il][18 j][17 h] f32
    //   [117504 .. end   ): h2w per-wave regions [8 wave][544 uints]
    __shared__ __align__(16) unsigned char UB[134912];
    float* Sbuf = (float*)UB;
    unsigned short* kvT = (unsigned short*)UB;       // [18 j][264 c] bf16 9504B
    float* qsw = (float*)UB;                         // 16 copies x 258 = 16512B
    float* t_s = (float*)(UB + 16512);               // [18 p][256 c] 18432B
    unsigned short* k_sb = (unsigned short*)(UB + 16512);  // k bf16 [256][20]
    unsigned int* h2w = (unsigned int*)(UB + 117504);// [8 wave][544 uints]
    float* wred = (float*)(UB + 39168);              // S1 region: 512x18 f32

    // ---- stage 0 ----
    if (tid < 256) {
        const float qv = q[b * 256 + tid];
        qf_s[tid] = qv;
        q_sb[tid] = (unsigned short)f2bf(qv * 0.25f);
    }
    for (int u = tid; u < 4128; u += 512) {
        const int r = u / 258, i = u - r * 258;
        qsw[u] = (i < 256) ? q[b * 256 + i] : 0.f;
    }
    if (tid < 312) {
        const int iy = tid / 26;
        lutxy[tid] = (unsigned int)(tid - iy * 26) | ((unsigned int)iy << 16);
    }
    if (tid < 64) b2_s[tid] = cb2[tid];
    if (tid < 16) b3_s[tid] = cb3[tid];
    if (tid >= 64 && tid < 96) {                     // CPB layer-1 weight table
        const int t2 = tid - 64;
        const int qdi = t2 >> 3, kp = t2 & 7;
        const int kk0 = 2 * kp, kk1 = 2 * kp + 1;
        const int kid0 = (kk0 < 8) ? (qdi * 8 + kk0) : (32 + qdi * 8 + kk0 - 8);
        const int kid1 = (kk1 < 8) ? (qdi * 8 + kk1) : (32 + qdi * 8 + kk1 - 8);
        w1p[qdi][kp][0] = cw1[kid0 * 2];
        w1p[qdi][kp][1] = cw1[kid0 * 2 + 1];
        w1p[qdi][kp][2] = cb1[kid0];
        w1p[qdi][kp][3] = cw1[kid1 * 2];
        w1p[qdi][kp][4] = cw1[kid1 * 2 + 1];
        w1p[qdi][kp][5] = cb1[kid1];
    }
    __syncthreads();

    // ---- depthwise conv 6x6 s4 p1 + GELU -> t_s ----
    {
        const int c = tid & 255, g = tid >> 8;     // g: jw-half
        float wreg[36];
        const float4* wdw4 = (const float4*)w_dw;  // [c][36] contiguous
        #pragma unroll
        for (int i = 0; i < 9; ++i) {
            const float4 t4 = wdw4[c * 9 + i];
            wreg[i * 4 + 0] = t4.x; wreg[i * 4 + 1] = t4.y;
            wreg[i * 4 + 2] = t4.z; wreg[i * 4 + 3] = t4.w;
        }
        float acc[9];
        const float bv = b_dw[c];
        #pragma unroll
        for (int a = 0; a < 9; ++a) acc[a] = bv;
        const int cb = (c * 56) & 255;
        const int cp = (c & 15) * 258;
        for (int jh = 0; jh < 3; ++jh) {
            for (int kh = 0; kh < 6; ++kh) {
                const int ih = jh * 4 - 1 + kh;
                if (ih < 0 || ih >= 12) continue;
                const int rb = ih * 26;
                #pragma unroll
                for (int jwl = 0; jwl < 3; ++jwl) {
                    const int jw = g * 3 + jwl;
                    #pragma unroll
                    for (int kw = 0; kw < 6; ++kw) {
                        const int iw = jw * 4 - 1 + kw;
                        if (iw < 0 || iw >= 26) continue;
                        acc[jh * 3 + jwl] += wreg[kh * 6 + kw] * qsw[cp + ((cb + rb + iw) & 255)];
                    }
                }
            }
        }
        #pragma unroll
        for (int a = 0; a < 9; ++a) {
            const int jh = a / 3, jwl = a - jh * 3;
            const int p = jh * 6 + g * 3 + jwl;
            const float v = acc[a];
            t_s[p * 256 + c] = 0.5f * v * (1.0f + erff(v * 0.70710678118654752f));
        }
    }
    __syncthreads();

    // ---- offsets: 36 dots over 256 channels ----
    for (int oi = w; oi < 36; oi += 8) {
        const int o = oi / 18, p = oi - o * 18;
        float s = 0.f;
        for (int c = lane; c < 256; c += 64) s += w_pw[o * 256 + c] * t_s[p * 256 + c];
        for (int d = 32; d > 0; d >>= 1) s += __shfl_down(s, d, 64);
        if (lane == 0) off_s[oi] = 4.0f * tanhf(s);
    }
    __syncthreads();

    // ---- grid coords + bilinear params ----
    if (tid < 18) {
        const int j = tid, jh = j / 6, jw = j - jh * 6;
        const float vg0 = (float)jw + off_s[j];
        const float vg1 = (float)jh + off_s[18 + j];
        const float n0 = 2.0f * vg0 / 2.0f - 1.0f;
        const float n1 = 2.0f * vg1 / 5.0f - 1.0f;
        n0_s[j] = n0; n1_s[j] = n1;
        const float xp = ((n0 + 1.0f) * 26.0f - 1.0f) * 0.5f;
        const float yp = ((n1 + 1.0f) * 12.0f - 1.0f) * 0.5f;
        const float x0 = floorf(xp), y0 = floorf(yp);
        sx0[j] = x0; sy0[j] = y0; swx[j] = xp - x0; swy[j] = yp - y0;
    }
    __syncthreads();

    // ---- bilinear sample -> kvT bf16 [j][264]; F0/F1 log tables ----
    {
        const int c = tid & 255, g = tid >> 8;
        const float* xb = x + ((size_t)b * 256 + c) * 312;
        for (int jj = 0; jj < 9; ++jj) {
            const int j = g * 9 + jj;
            const int x0 = (int)sx0[j], y0 = (int)sy0[j];
            const int x1 = x0 + 1, y1 = y0 + 1;
            const float wx1 = swx[j], wy1 = swy[j];
            const float wx0 = 1.f - wx1, wy0 = 1.f - wy1;
            const bool xv0 = (x0 >= 0) & (x0 < 26), xv1 = (x1 >= 0) & (x1 < 26);
            const bool yv0 = (y0 >= 0) & (y0 < 12), yv1 = (y1 >= 0) & (y1 < 12);
            const float v00 = (xv0 & yv0) ? xb[y0 * 26 + x0] : 0.f;
            const float v01 = (xv1 & yv0) ? xb[y0 * 26 + x1] : 0.f;
            const float v10 = (xv0 & yv1) ? xb[y1 * 26 + x0] : 0.f;
            const float v11 = (xv1 & yv1) ? xb[y1 * 26 + x1] : 0.f;
            const float val = wy0 * (wx0 * v00 + wx1 * v01) + wy1 * (wx0 * v10 + wx1 * v11);
            kvT[j * 264 + c] = (unsigned short)f2bf(val);
        }
    }
    for (int u = tid; u < 684; u += 512) {
        if (u < 468) {
            const int ixv = u / 18, j = u - ixv * 18;
            const float p0 = (float)ixv * (2.0f / 11.0f) - 1.0f - n0_s[j];
            F0[u] = copysignf(__logf(1.0f + fabsf(p0)), p0);
        } else {
            const int u2 = u - 468;
            const int iyv = u2 / 18, j = u2 - iyv * 18;
            const float p1 = (float)iyv * (2.0f / 25.0f) - 1.0f - n1_s[j];
            F1[u2] = copysignf(__logf(1.0f + fabsf(p1)), p1);
        }
    }
    __syncthreads();

    // ---- k/v projection via MFMA: wave w -> matrix (w&1), mtb = w>>1 ----
    {
        const int m2 = w & 1, mtb = w >> 1;
        const float4* wm4 = (const float4*)(m2 ? wv : wk);
        floatx4 pa[4][2];
        #pragma unroll
        for (int a = 0; a < 4; ++a) {
            pa[a][0] = (floatx4){0.f, 0.f, 0.f, 0.f};
            pa[a][1] = (floatx4){0.f, 0.f, 0.f, 0.f};
        }
        #pragma unroll 2
        for (int ks = 0; ks < 8; ++ks) {
            U16 b0, b1;
            b0.u = *(const uint4*)(kvT + n * 264 + ks * 32 + qd * 8);
            b1.u = make_uint4(0u, 0u, 0u, 0u);
            if (n < 2) b1.u = *(const uint4*)(kvT + (16 + n) * 264 + ks * 32 + qd * 8);
            #pragma unroll
            for (int mtl = 0; mtl < 4; ++mtl) {
                const int mt = mtb + mtl * 4;
                const int f4i = (mt * 16 + n) * 64 + ks * 8 + qd * 2;
                U16 A; A.u = pack8(wm4[f4i], wm4[f4i + 1]);
                pa[mtl][0] = MFMA(A.s, b0.s, pa[mtl][0]);
                pa[mtl][1] = MFMA(A.s, b1.s, pa[mtl][1]);
            }
        }
        unsigned short* dst = m2 ? v_sb : k_sb;
        #pragma unroll
        for (int mtl = 0; mtl < 4; ++mtl) {
            const int mt = mtb + mtl * 4;
            #pragma unroll
            for (int r = 0; r < 4; ++r) {
                const int o = mt * 16 + qd * 4 + r;
                dst[o * 20 + n] = (unsigned short)f2bf(pa[mtl][0][r]);
                if (n < 2) dst[o * 20 + 16 + n] = (unsigned short)f2bf(pa[mtl][1][r]);
            }
        }
    }
    __syncthreads();

    // ---- per-lane weight fragments (late load) ----
    uint4 W2f[4][2], W3f[2];
    {
        const float4* cw2_4 = (const float4*)cw2;
        #pragma unroll
        for (int mtl = 0; mtl < 4; ++mtl)
            #pragma unroll
            for (int ks = 0; ks < 2; ++ks) {
                const int base = (mtl * 16 + n) * 16 + ks * 8 + qd * 2;
                W2f[mtl][ks] = pack8(cw2_4[base], cw2_4[base + 1]);
            }
        const float4* cw3_4 = (const float4*)cw3;
        #pragma unroll
        for (int ks = 0; ks < 2; ++ks) {
            const int base = n * 16 + ks * 8 + qd * 2;
            W3f[ks] = pack8(cw3_4[base], cw3_4[base + 1]);
        }
    }

    // ---- Bk fragments for sim (wave w: heads 2w, 2w+1) ----
    uint4 BkU[2][2];
    #pragma unroll
    for (int hh = 0; hh < 2; ++hh)
        #pragma unroll
        for (int jt = 0; jt < 2; ++jt) {
            unsigned int u0 = 0, u1 = 0, u2 = 0, u3 = 0;
            if (qd < 2 && (jt == 0 || n < 2)) {
                const int h = w * 2 + hh;
                const int j = jt * 16 + n;
                const int cb0 = (h * 16 + qd * 8) * 20 + j;
                u0 = (unsigned)k_sb[cb0] | ((unsigned)k_sb[cb0 + 20] << 16);
                u1 = (unsigned)k_sb[cb0 + 40] | ((unsigned)k_sb[cb0 + 60] << 16);
                u2 = (unsigned)k_sb[cb0 + 80] | ((unsigned)k_sb[cb0 + 100] << 16);
                u3 = (unsigned)k_sb[cb0 + 120] | ((unsigned)k_sb[cb0 + 140] << 16);
            }
            BkU[hh][jt] = make_uint4(u0, u1, u2, u3);
        }
    __syncthreads();   // k_sb dead; S triple buffer + h2w live from here

    // ---- 3-stage pipelined chunk loop: 12 intervals, 1 barrier each ----
    float wAcc[18];
    #pragma unroll
    for (int j = 0; j < 18; ++j) wAcc[j] = 0.f;

    auto soft_acc = [&](int chp, const float* Sp) {
        const int il = tid >> 4, h = tid & 15;
        const int CIp = (chp == 9) ? 24 : 32;
        if (il < CIp) {
            const float cwv = conv_w[chp * 32 + il];
            float lv[18];
            const float* row = Sp + (il * 18) * 17 + h;
            #pragma unroll
            for (int j = 0; j < 18; ++j) lv[j] = row[j * 17];
            float m = lv[0];
            #pragma unroll
            for (int j = 1; j < 18; ++j) m = fmaxf(m, lv[j]);
            float s = 0.f;
            #pragma unroll
            for (int j = 0; j < 18; ++j) { lv[j] = __expf(lv[j] - m); s += lv[j]; }
            const float wgt = cwv / s;
            #pragma unroll
            for (int j = 0; j < 18; ++j) wAcc[j] = fmaf(wgt, lv[j], wAcc[j]);
        }
    };

    for (int t = 0; t < 12; ++t) {
        // (a) sim(t) -> S[t%3]
        if (t < 10) {
            float* Sc = Sbuf + (t % 3) * 9792;
            const int ibase = t * 32;
            #pragma unroll
            for (int hh = 0; hh < 2; ++hh) {
                const int h = w * 2 + hh;
                const int base = h * 16 + qd * 8;
                #pragma unroll
                for (int ig = 0; ig < 2; ++ig) {
                    unsigned int a0 = 0, a1 = 0, a2 = 0, a3u = 0;
                    if (qd < 2) {
                        const int ii = ibase + ig * 16 + n;
                        a0 = (unsigned)q_sb[((base + 0) * 56 + ii) & 255] |
                             ((unsigned)q_sb[((base + 1) * 56 + ii) & 255] << 16);
                        a1 = (unsigned)q_sb[((base + 2) * 56 + ii) & 255] |
                             ((unsigned)q_sb[((base + 3) * 56 + ii) & 255] << 16);
                        a2 = (unsigned)q_sb[((base + 4) * 56 + ii) & 255] |
                             ((unsigned)q_sb[((base + 5) * 56 + ii) & 255] << 16);
                        a3u = (unsigned)q_sb[((base + 6) * 56 + ii) & 255] |
                              ((unsigned)q_sb[((base + 7) * 56 + ii) & 255] << 16);
                    }
                    U16 Af; Af.u = make_uint4(a0, a1, a2, a3u);
                    #pragma unroll
                    for (int jt = 0; jt < 2; ++jt) {
                        U16 Bf; Bf.u = BkU[hh][jt];
                        floatx4 D = {0.f, 0.f, 0.f, 0.f};
                        D = MFMA(Af.s, Bf.s, D);
                        const int j = jt * 16 + n;
                        if (j < 18) {
                            #pragma unroll
                            for (int r = 0; r < 4; ++r)
                                Sc[((ig * 16 + qd * 4 + r) * 18 + j) * 17 + h] = D[r];
                        }
                    }
                }
            }
        }
        // (b) mlp(t-1) RMW S[(t-1)%3]
        if (t >= 1 && t < 11) {
            const int chm = t - 1;
            float* Sm = Sbuf + (chm % 3) * 9792;
            const int ibase = chm * 32;
            auto mlp1 = [&](int tt) {
                const int ig = (tt >= 18) ? 1 : 0;
                const int j = tt - ig * 18;
                const int i0 = ibase + ig * 16 + n;
                const unsigned int lv2 = lutxy[(i0 < 312) ? i0 : 311];
                const int ix = (int)(lv2 & 0xffffu), iy = (int)(lv2 >> 16);
                const float f0 = F0[ix * 18 + j];
                const float f1 = F1[iy * 18 + j];
                U16 ub0, ub1;
                {
                    unsigned int uu[8];
                    #pragma unroll
                    for (int kp = 0; kp < 8; ++kp) {
                        const float* wp = &w1p[qd][kp][0];
                        const float ha = fmaxf(fmaf(wp[0], f0, fmaf(wp[1], f1, wp[2])), 0.f);
                        const float hb = fmaxf(fmaf(wp[3], f0, fmaf(wp[4], f1, wp[5])), 0.f);
                        uu[kp] = pk2(ha, hb);
                    }
                    ub0.u = make_uint4(uu[0], uu[1], uu[2], uu[3]);
                    ub1.u = make_uint4(uu[4], uu[5], uu[6], uu[7]);
                }
                // GEMM2 -> h2 to this wave's LDS region
                unsigned int* hw = h2w + w * 544 + n * 34;
                #pragma unroll
                for (int mtl = 0; mtl < 4; ++mtl) {
                    U16 A0, A1; A0.u = W2f[mtl][0]; A1.u = W2f[mtl][1];
                    floatx4 acc = {0.f, 0.f, 0.f, 0.f};
                    acc = MFMA(A0.s, ub0.s, acc);
                    acc = MFMA(A1.s, ub1.s, acc);
                    const float e0 = fmaxf(acc[0] + b2_s[mtl*16 + qd*4 + 0], 0.f);
                    const float e1 = fmaxf(acc[1] + b2_s[mtl*16 + qd*4 + 1], 0.f);
                    const float e2 = fmaxf(acc[2] + b2_s[mtl*16 + qd*4 + 2], 0.f);
                    const float e3 = fmaxf(acc[3] + b2_s[mtl*16 + qd*4 + 3], 0.f);
                    hw[mtl * 8 + qd * 2]     = pk2(e0, e1);
                    hw[mtl * 8 + qd * 2 + 1] = pk2(e2, e3);
                }
                // GEMM3 (wave-local lgkm drain)
                const unsigned int* hwr = h2w + w * 544;
                U16 uc0, uc1;
                uc0.u = *(const uint4*)(hwr + n * 34 + qd * 4);
                uc1.u = *(const uint4*)(hwr + n * 34 + 16 + qd * 4);
                U16 A0, A1; A0.u = W3f[0]; A1.u = W3f[1];
                floatx4 a3 = {0.f, 0.f, 0.f, 0.f};
                a3 = MFMA(A0.s, uc0.s, a3);
                a3 = MFMA(A1.s, uc1.s, a3);
                float* sp = Sm + ((ig * 16 + n) * 18 + j) * 17 + qd * 4;
                #pragma unroll
                for (int r = 0; r < 4; ++r) sp[r] = a3[r] + b3_s[qd * 4 + r] + sp[r];
            };
            mlp1(w);
            mlp1(w + 8);
            mlp1(w + 16);
            mlp1(w + 24);
            if (w < 4) mlp1(32 + w);
        }
        // (c) soft(t-2) reads S[(t-2)%3]
        if (t >= 2) soft_acc(t - 2, Sbuf + ((t - 2) % 3) * 9792);
        __syncthreads();
    }

    // ---- reduce wAcc over 32 il-slots -> wA_s[h][j]; conv_w sum ----
    // wred sits in S1 region; last soft read S0 (chunk 9, 9%3=0). Barrier
    // from the final interval separates.
    #pragma unroll
    for (int j = 0; j < 18; ++j) wred[tid * 18 + j] = wAcc[j];
    {
        float v = 0.f;
        for (int u = tid; u < 312; u += 512) v += conv_w[u];
        for (int d = 32; d > 0; d >>= 1) v += __shfl_down(v, d, 64);
        if (lane == 0) redb[w] = v;
    }
    __syncthreads();
    for (int u = tid; u < 288; u += 512) {
        const int h = u / 18, j = u - h * 18;
        float s = 0.f;
        #pragma unroll
        for (int sl = 0; sl < 32; ++sl) s += wred[(sl * 16 + h) * 18 + j];
        wA_s[u] = s;
    }
    __syncthreads();

    // ---- m[c] = sum_j wA[h][j] * v[c][j] ----
    if (tid < 256) {
        const int hb = (tid >> 4) * 18;
        float acc = 0.f;
        #pragma unroll
        for (int j = 0; j < 18; ++j) acc += wA_s[hb + j] * bf2f(v_sb[tid * 20 + j]);
        m_s[tid] = acc;
    }
    __syncthreads();

    float Ssum = 0.f;
    #pragma unroll
    for (int i = 0; i < 8; ++i) Ssum += redb[i];

    // ---- pooled = w_out . m  (8 waves x 32 rows, coalesced float4) ----
    {
        const float4 mm = *(const float4*)(m_s + lane * 4);
        for (int ol = 0; ol < 32; ++ol) {
            const int o = w * 32 + ol;
            const float4 wq = *(const float4*)(w_out + o * 256 + lane * 4);
            float d = wq.x * mm.x + wq.y * mm.y + wq.z * mm.z + wq.w * mm.w;
            for (int dd = 32; dd > 0; dd >>= 1) d += __shfl_down(d, dd, 64);
            if (lane == 0) pooled_s[o] = d;
        }
    }
    __syncthreads();

    // ---- residual + LayerNorm (first 4 waves) ----
    if (tid < 256) {
        const float y = pooled_s[tid] + b_out[tid] * Ssum + conv_b[0] + qf_s[tid];
        float s1 = y, s2 = y * y;
        for (int d = 32; d > 0; d >>= 1) { s1 += __shfl_down(s1, d, 64); s2 += __shfl_down(s2, d, 64); }
        if (lane == 0) { redb[16 + w] = s1; redb[20 + w] = s2; }
    }
    __syncthreads();
    if (tid < 256) {
        const float y = pooled_s[tid] + b_out[tid] * Ssum + conv_b[0] + qf_s[tid];
        const float S1 = redb[16] + redb[17] + redb[18] + redb[19];
        const float S2 = redb[20] + redb[21] + redb[22] + redb[23];
        const float mu = S1 * (1.0f / 256.0f);
        const float var = S2 * (1.0f / 256.0f) - mu * mu;
        out[b * 256 + tid] = (y - mu) * rsqrtf(var + 1e-5f) * ln_g[tid] + ln_b[tid];
    }
}

// ===========================================================================
extern "C" void kernel_launch(void* const* d_in, const int* in_sizes, int n_in,
                              void* d_out, int out_size, void* d_ws, size_t ws_size,
                              hipStream_t stream) {
    const float* x       = (const float*)d_in[0];
    const float* q       = (const float*)d_in[1];
    const float* w_dw    = (const float*)d_in[2];
    const float* b_dwp   = (const float*)d_in[3];
    const float* w_pw    = (const float*)d_in[4];
    const float* wk      = (const float*)d_in[5];
    const float* wv      = (const float*)d_in[6];
    const float* w_out   = (const float*)d_in[7];
    const float* b_out   = (const float*)d_in[8];
    const float* cw1     = (const float*)d_in[9];
    const float* cb1     = (const float*)d_in[10];
    const float* cw2     = (const float*)d_in[11];
    const float* cb2     = (const float*)d_in[12];
    const float* cw3     = (const float*)d_in[13];
    const float* cb3     = (const float*)d_in[14];
    const float* conv_w  = (const float*)d_in[15];
    const float* conv_b  = (const float*)d_in[16];
    const float* ln_g    = (const float*)d_in[17];
    const float* ln_b    = (const float*)d_in[18];
    float* out = (float*)d_out;

    k_all<<<256, 512, 0, stream>>>(x, q, w_dw, b_dwp, w_pw, wk, wv, w_out, b_out,
                                   cw1, cb1, cw2, cb2, cw3, cb3,
                                   conv_w, conv_b, ln_g, ln_b, out);
}

// Round 9
// 252.169 us; speedup vs baseline: 1.9882x; 1.0276x over previous
//
#include <hip/hip_runtime.h>
#include <hip/hip_bf16.h>
#include <math.h>

// ---------------------------------------------------------------------------
// DIM=256 HEADS=16 DHEAD=16 H=12 W=26 (HW=312)  Hk=3 Wk=6 (J=18)  B=256
// q_map[b,c,s] = q[b,(c*56+s)&255]
// Round 16: r15 3-buffer pipeline + GEMM3 via K=16 MFMA chaining.
// r15 post-mortem: barriers were never the cost (20->12 saved 3us); the
// mlp h2w LDS write->lgkm->read transpose roundtrip (~200+ cyc exposed
// per mlp1 x 45/wave) is. Fix: v_mfma_f32_16x16x16bf16_1k has B-frag
// layout k=qd*4+j == GEMM2's D-row granularity, so GEMM2's relu'd
// accumulator packs DIRECTLY into GEMM3's B fragment (kc=mtl), fused in
// the mtl loop. No LDS transpose, no h2w region (-17KB LDS), no drains.
// W3 A-frags repacked for K=16 (same 8 regs). D layout 16x16x16 ==
// 16x16x32 (shape-determined) -> S RMW epilogue unchanged.
// Everything else identical to r15 (passed, absmax 0.015625).
// ---------------------------------------------------------------------------

typedef __attribute__((ext_vector_type(8))) short short8;   // 8 bf16
typedef __attribute__((ext_vector_type(4))) short s4bf;     // 4 bf16
typedef __attribute__((ext_vector_type(4))) float floatx4;

union U16 { uint4 u; short8 s; };
union U8b { unsigned int u[2]; s4bf s; };

#define MFMA(A, B, C) __builtin_amdgcn_mfma_f32_16x16x32_bf16((A), (B), (C), 0, 0, 0)
#define MFMA16(A, B, C) __builtin_amdgcn_mfma_f32_16x16x16bf16_1k((A), (B), (C), 0, 0, 0)

__device__ __forceinline__ unsigned int f2bf(float f) {   // RNE f32->bf16 (low 16)
    unsigned int u = __float_as_uint(f);
    u += 0x7fffu + ((u >> 16) & 1u);
    return u >> 16;
}
__device__ __forceinline__ unsigned int pk2(float a, float b) {   // HW cvt_pk
    __hip_bfloat162 h = __float22bfloat162_rn(make_float2(a, b));
    union { __hip_bfloat162 h; unsigned int u; } cv; cv.h = h;
    return cv.u;
}
__device__ __forceinline__ float bf2f(unsigned short v) {
    return __uint_as_float((unsigned int)v << 16);
}
__device__ __forceinline__ uint4 pack8(float4 a, float4 b) {
    uint4 r;
    r.x = pk2(a.x, a.y); r.y = pk2(a.z, a.w);
    r.z = pk2(b.x, b.y); r.w = pk2(b.z, b.w);
    return r;
}

// ===========================================================================
__global__ __launch_bounds__(512, 2) void k_all(
    const float* __restrict__ x, const float* __restrict__ q,
    const float* __restrict__ w_dw, const float* __restrict__ b_dw,
    const float* __restrict__ w_pw,
    const float* __restrict__ wk, const float* __restrict__ wv,
    const float* __restrict__ w_out, const float* __restrict__ b_out,
    const float* __restrict__ cw1, const float* __restrict__ cb1,
    const float* __restrict__ cw2, const float* __restrict__ cb2,
    const float* __restrict__ cw3, const float* __restrict__ cb3,
    const float* __restrict__ conv_w, const float* __restrict__ conv_b,
    const float* __restrict__ ln_g, const float* __restrict__ ln_b,
    float* __restrict__ out)
{
    const int b = blockIdx.x, tid = threadIdx.x;
    const int w = tid >> 6, lane = tid & 63;
    const int n = lane & 15, qd = lane >> 4;

    // ---- persistent LDS (~20.9 KB) ----
    __shared__ float qf_s[256];
    __shared__ unsigned short q_sb[256];            // bf16(q*0.25)
    __shared__ unsigned short v_sb[5120];           // v bf16 [256][20]
    __shared__ float F0[468], F1[216];              // log tables [26][18], [12][18]
    __shared__ unsigned int lutxy[312];             // ix | iy<<16
    __shared__ float off_s[36], n0_s[18], n1_s[18];
    __shared__ float sx0[18], sy0[18], swx[18], swy[18];
    __shared__ float b2_s[64], b3_s[16];
    __shared__ __align__(16) float w1p[4][8][8];    // [qd][kp][6 used]
    __shared__ float wA_s[288];
    __shared__ __align__(16) float m_s[256];
    __shared__ float pooled_s[256], redb[24];
    // ---- union region (117504 B): S triple buffer, 3 x [32][18][17] f32 ----
    __shared__ __align__(16) unsigned char UB[117504];
    float* Sbuf = (float*)UB;
    unsigned short* kvT = (unsigned short*)UB;       // [18 j][264 c] bf16 9504B
    float* qsw = (float*)UB;                         // 16 copies x 258 = 16512B
    float* t_s = (float*)(UB + 16512);               // [18 p][256 c] 18432B
    unsigned short* k_sb = (unsigned short*)(UB + 16512);  // k bf16 [256][20]
    float* wred = (float*)(UB + 39168);              // S1 region: 512x18 f32

    // ---- stage 0 ----
    if (tid < 256) {
        const float qv = q[b * 256 + tid];
        qf_s[tid] = qv;
        q_sb[tid] = (unsigned short)f2bf(qv * 0.25f);
    }
    for (int u = tid; u < 4128; u += 512) {
        const int r = u / 258, i = u - r * 258;
        qsw[u] = (i < 256) ? q[b * 256 + i] : 0.f;
    }
    if (tid < 312) {
        const int iy = tid / 26;
        lutxy[tid] = (unsigned int)(tid - iy * 26) | ((unsigned int)iy << 16);
    }
    if (tid < 64) b2_s[tid] = cb2[tid];
    if (tid < 16) b3_s[tid] = cb3[tid];
    if (tid >= 64 && tid < 96) {                     // CPB layer-1 weight table
        const int t2 = tid - 64;
        const int qdi = t2 >> 3, kp = t2 & 7;
        const int kk0 = 2 * kp, kk1 = 2 * kp + 1;
        const int kid0 = (kk0 < 8) ? (qdi * 8 + kk0) : (32 + qdi * 8 + kk0 - 8);
        const int kid1 = (kk1 < 8) ? (qdi * 8 + kk1) : (32 + qdi * 8 + kk1 - 8);
        w1p[qdi][kp][0] = cw1[kid0 * 2];
        w1p[qdi][kp][1] = cw1[kid0 * 2 + 1];
        w1p[qdi][kp][2] = cb1[kid0];
        w1p[qdi][kp][3] = cw1[kid1 * 2];
        w1p[qdi][kp][4] = cw1[kid1 * 2 + 1];
        w1p[qdi][kp][5] = cb1[kid1];
    }
    __syncthreads();

    // ---- depthwise conv 6x6 s4 p1 + GELU -> t_s ----
    {
        const int c = tid & 255, g = tid >> 8;     // g: jw-half
        float wreg[36];
        const float4* wdw4 = (const float4*)w_dw;  // [c][36] contiguous
        #pragma unroll
        for (int i = 0; i < 9; ++i) {
            const float4 t4 = wdw4[c * 9 + i];
            wreg[i * 4 + 0] = t4.x; wreg[i * 4 + 1] = t4.y;
            wreg[i * 4 + 2] = t4.z; wreg[i * 4 + 3] = t4.w;
        }
        float acc[9];
        const float bv = b_dw[c];
        #pragma unroll
        for (int a = 0; a < 9; ++a) acc[a] = bv;
        const int cb = (c * 56) & 255;
        const int cp = (c & 15) * 258;
        for (int jh = 0; jh < 3; ++jh) {
            for (int kh = 0; kh < 6; ++kh) {
                const int ih = jh * 4 - 1 + kh;
                if (ih < 0 || ih >= 12) continue;
                const int rb = ih * 26;
                #pragma unroll
                for (int jwl = 0; jwl < 3; ++jwl) {
                    const int jw = g * 3 + jwl;
                    #pragma unroll
                    for (int kw = 0; kw < 6; ++kw) {
                        const int iw = jw * 4 - 1 + kw;
                        if (iw < 0 || iw >= 26) continue;
                        acc[jh * 3 + jwl] += wreg[kh * 6 + kw] * qsw[cp + ((cb + rb + iw) & 255)];
                    }
                }
            }
        }
        #pragma unroll
        for (int a = 0; a < 9; ++a) {
            const int jh = a / 3, jwl = a - jh * 3;
            const int p = jh * 6 + g * 3 + jwl;
            const float v = acc[a];
            t_s[p * 256 + c] = 0.5f * v * (1.0f + erff(v * 0.70710678118654752f));
        }
    }
    __syncthreads();

    // ---- offsets: 36 dots over 256 channels ----
    for (int oi = w; oi < 36; oi += 8) {
        const int o = oi / 18, p = oi - o * 18;
        float s = 0.f;
        for (int c = lane; c < 256; c += 64) s += w_pw[o * 256 + c] * t_s[p * 256 + c];
        for (int d = 32; d > 0; d >>= 1) s += __shfl_down(s, d, 64);
        if (lane == 0) off_s[oi] = 4.0f * tanhf(s);
    }
    __syncthreads();

    // ---- grid coords + bilinear params ----
    if (tid < 18) {
        const int j = tid, jh = j / 6, jw = j - jh * 6;
        const float vg0 = (float)jw + off_s[j];
        const float vg1 = (float)jh + off_s[18 + j];
        const float n0 = 2.0f * vg0 / 2.0f - 1.0f;
        const float n1 = 2.0f * vg1 / 5.0f - 1.0f;
        n0_s[j] = n0; n1_s[j] = n1;
        const float xp = ((n0 + 1.0f) * 26.0f - 1.0f) * 0.5f;
        const float yp = ((n1 + 1.0f) * 12.0f - 1.0f) * 0.5f;
        const float x0 = floorf(xp), y0 = floorf(yp);
        sx0[j] = x0; sy0[j] = y0; swx[j] = xp - x0; swy[j] = yp - y0;
    }
    __syncthreads();

    // ---- bilinear sample -> kvT bf16 [j][264]; F0/F1 log tables ----
    {
        const int c = tid & 255, g = tid >> 8;
        const float* xb = x + ((size_t)b * 256 + c) * 312;
        for (int jj = 0; jj < 9; ++jj) {
            const int j = g * 9 + jj;
            const int x0 = (int)sx0[j], y0 = (int)sy0[j];
            const int x1 = x0 + 1, y1 = y0 + 1;
            const float wx1 = swx[j], wy1 = swy[j];
            const float wx0 = 1.f - wx1, wy0 = 1.f - wy1;
            const bool xv0 = (x0 >= 0) & (x0 < 26), xv1 = (x1 >= 0) & (x1 < 26);
            const bool yv0 = (y0 >= 0) & (y0 < 12), yv1 = (y1 >= 0) & (y1 < 12);
            const float v00 = (xv0 & yv0) ? xb[y0 * 26 + x0] : 0.f;
            const float v01 = (xv1 & yv0) ? xb[y0 * 26 + x1] : 0.f;
            const float v10 = (xv0 & yv1) ? xb[y1 * 26 + x0] : 0.f;
            const float v11 = (xv1 & yv1) ? xb[y1 * 26 + x1] : 0.f;
            const float val = wy0 * (wx0 * v00 + wx1 * v01) + wy1 * (wx0 * v10 + wx1 * v11);
            kvT[j * 264 + c] = (unsigned short)f2bf(val);
        }
    }
    for (int u = tid; u < 684; u += 512) {
        if (u < 468) {
            const int ixv = u / 18, j = u - ixv * 18;
            const float p0 = (float)ixv * (2.0f / 11.0f) - 1.0f - n0_s[j];
            F0[u] = copysignf(__logf(1.0f + fabsf(p0)), p0);
        } else {
            const int u2 = u - 468;
            const int iyv = u2 / 18, j = u2 - iyv * 18;
            const float p1 = (float)iyv * (2.0f / 25.0f) - 1.0f - n1_s[j];
            F1[u2] = copysignf(__logf(1.0f + fabsf(p1)), p1);
        }
    }
    __syncthreads();

    // ---- k/v projection via MFMA: wave w -> matrix (w&1), mtb = w>>1 ----
    {
        const int m2 = w & 1, mtb = w >> 1;
        const float4* wm4 = (const float4*)(m2 ? wv : wk);
        floatx4 pa[4][2];
        #pragma unroll
        for (int a = 0; a < 4; ++a) {
            pa[a][0] = (floatx4){0.f, 0.f, 0.f, 0.f};
            pa[a][1] = (floatx4){0.f, 0.f, 0.f, 0.f};
        }
        #pragma unroll 2
        for (int ks = 0; ks < 8; ++ks) {
            U16 b0, b1;
            b0.u = *(const uint4*)(kvT + n * 264 + ks * 32 + qd * 8);
            b1.u = make_uint4(0u, 0u, 0u, 0u);
            if (n < 2) b1.u = *(const uint4*)(kvT + (16 + n) * 264 + ks * 32 + qd * 8);
            #pragma unroll
            for (int mtl = 0; mtl < 4; ++mtl) {
                const int mt = mtb + mtl * 4;
                const int f4i = (mt * 16 + n) * 64 + ks * 8 + qd * 2;
                U16 A; A.u = pack8(wm4[f4i], wm4[f4i + 1]);
                pa[mtl][0] = MFMA(A.s, b0.s, pa[mtl][0]);
                pa[mtl][1] = MFMA(A.s, b1.s, pa[mtl][1]);
            }
        }
        unsigned short* dst = m2 ? v_sb : k_sb;
        #pragma unroll
        for (int mtl = 0; mtl < 4; ++mtl) {
            const int mt = mtb + mtl * 4;
            #pragma unroll
            for (int r = 0; r < 4; ++r) {
                const int o = mt * 16 + qd * 4 + r;
                dst[o * 20 + n] = (unsigned short)f2bf(pa[mtl][0][r]);
                if (n < 2) dst[o * 20 + 16 + n] = (unsigned short)f2bf(pa[mtl][1][r]);
            }
        }
    }
    __syncthreads();

    // ---- per-lane weight fragments (late load) ----
    uint4 W2f[4][2];
    unsigned int W3h[4][2];                          // K=16 A-frags for GEMM3
    {
        const float4* cw2_4 = (const float4*)cw2;
        #pragma unroll
        for (int mtl = 0; mtl < 4; ++mtl)
            #pragma unroll
            for (int ks = 0; ks < 2; ++ks) {
                const int base = (mtl * 16 + n) * 16 + ks * 8 + qd * 2;
                W2f[mtl][ks] = pack8(cw2_4[base], cw2_4[base + 1]);
            }
        const float4* cw3_4 = (const float4*)cw3;
        #pragma unroll
        for (int kc = 0; kc < 4; ++kc) {
            const float4 v = cw3_4[n * 16 + kc * 4 + qd];  // cw3[n*64+kc*16+qd*4..]
            W3h[kc][0] = pk2(v.x, v.y);
            W3h[kc][1] = pk2(v.z, v.w);
        }
    }

    // ---- Bk fragments for sim (wave w: heads 2w, 2w+1) ----
    uint4 BkU[2][2];
    #pragma unroll
    for (int hh = 0; hh < 2; ++hh)
        #pragma unroll
        for (int jt = 0; jt < 2; ++jt) {
            unsigned int u0 = 0, u1 = 0, u2 = 0, u3 = 0;
            if (qd < 2 && (jt == 0 || n < 2)) {
                const int h = w * 2 + hh;
                const int j = jt * 16 + n;
                const int cb0 = (h * 16 + qd * 8) * 20 + j;
                u0 = (unsigned)k_sb[cb0] | ((unsigned)k_sb[cb0 + 20] << 16);
                u1 = (unsigned)k_sb[cb0 + 40] | ((unsigned)k_sb[cb0 + 60] << 16);
                u2 = (unsigned)k_sb[cb0 + 80] | ((unsigned)k_sb[cb0 + 100] << 16);
                u3 = (unsigned)k_sb[cb0 + 120] | ((unsigned)k_sb[cb0 + 140] << 16);
            }
            BkU[hh][jt] = make_uint4(u0, u1, u2, u3);
        }
    __syncthreads();   // k_sb dead; S triple buffer live from here

    // ---- 3-stage pipelined chunk loop: 12 intervals, 1 barrier each ----
    float wAcc[18];
    #pragma unroll
    for (int j = 0; j < 18; ++j) wAcc[j] = 0.f;

    auto soft_acc = [&](int chp, const float* Sp) {
        const int il = tid >> 4, h = tid & 15;
        const int CIp = (chp == 9) ? 24 : 32;
        if (il < CIp) {
            const float cwv = conv_w[chp * 32 + il];
            float lv[18];
            const float* row = Sp + (il * 18) * 17 + h;
            #pragma unroll
            for (int j = 0; j < 18; ++j) lv[j] = row[j * 17];
            float m = lv[0];
            #pragma unroll
            for (int j = 1; j < 18; ++j) m = fmaxf(m, lv[j]);
            float s = 0.f;
            #pragma unroll
            for (int j = 0; j < 18; ++j) { lv[j] = __expf(lv[j] - m); s += lv[j]; }
            const float wgt = cwv / s;
            #pragma unroll
            for (int j = 0; j < 18; ++j) wAcc[j] = fmaf(wgt, lv[j], wAcc[j]);
        }
    };

    for (int t = 0; t < 12; ++t) {
        // (a) sim(t) -> S[t%3]
        if (t < 10) {
            float* Sc = Sbuf + (t % 3) * 9792;
            const int ibase = t * 32;
            #pragma unroll
            for (int hh = 0; hh < 2; ++hh) {
                const int h = w * 2 + hh;
                const int base = h * 16 + qd * 8;
                #pragma unroll
                for (int ig = 0; ig < 2; ++ig) {
                    unsigned int a0 = 0, a1 = 0, a2 = 0, a3u = 0;
                    if (qd < 2) {
                        const int ii = ibase + ig * 16 + n;
                        a0 = (unsigned)q_sb[((base + 0) * 56 + ii) & 255] |
                             ((unsigned)q_sb[((base + 1) * 56 + ii) & 255] << 16);
                        a1 = (unsigned)q_sb[((base + 2) * 56 + ii) & 255] |
                             ((unsigned)q_sb[((base + 3) * 56 + ii) & 255] << 16);
                        a2 = (unsigned)q_sb[((base + 4) * 56 + ii) & 255] |
                             ((unsigned)q_sb[((base + 5) * 56 + ii) & 255] << 16);
                        a3u = (unsigned)q_sb[((base + 6) * 56 + ii) & 255] |
                              ((unsigned)q_sb[((base + 7) * 56 + ii) & 255] << 16);
                    }
                    U16 Af; Af.u = make_uint4(a0, a1, a2, a3u);
                    #pragma unroll
                    for (int jt = 0; jt < 2; ++jt) {
                        U16 Bf; Bf.u = BkU[hh][jt];
                        floatx4 D = {0.f, 0.f, 0.f, 0.f};
                        D = MFMA(Af.s, Bf.s, D);
                        const int j = jt * 16 + n;
                        if (j < 18) {
                            #pragma unroll
                            for (int r = 0; r < 4; ++r)
                                Sc[((ig * 16 + qd * 4 + r) * 18 + j) * 17 + h] = D[r];
                        }
                    }
                }
            }
        }
        // (b) mlp(t-1) RMW S[(t-1)%3] — GEMM2->GEMM3 fused, no LDS transpose
        if (t >= 1 && t < 11) {
            const int chm = t - 1;
            float* Sm = Sbuf + (chm % 3) * 9792;
            const int ibase = chm * 32;
            auto mlp1 = [&](int tt) {
                const int ig = (tt >= 18) ? 1 : 0;
                const int j = tt - ig * 18;
                const int i0 = ibase + ig * 16 + n;
                const unsigned int lv2 = lutxy[(i0 < 312) ? i0 : 311];
                const int ix = (int)(lv2 & 0xffffu), iy = (int)(lv2 >> 16);
                const float f0 = F0[ix * 18 + j];
                const float f1 = F1[iy * 18 + j];
                U16 ub0, ub1;
                {
                    unsigned int uu[8];
                    #pragma unroll
                    for (int kp = 0; kp < 8; ++kp) {
                        const float* wp = &w1p[qd][kp][0];
                        const float ha = fmaxf(fmaf(wp[0], f0, fmaf(wp[1], f1, wp[2])), 0.f);
                        const float hb = fmaxf(fmaf(wp[3], f0, fmaf(wp[4], f1, wp[5])), 0.f);
                        uu[kp] = pk2(ha, hb);
                    }
                    ub0.u = make_uint4(uu[0], uu[1], uu[2], uu[3]);
                    ub1.u = make_uint4(uu[4], uu[5], uu[6], uu[7]);
                }
                // GEMM2 (K=32) -> relu -> pack -> GEMM3 partial (K=16), fused
                floatx4 a3 = {0.f, 0.f, 0.f, 0.f};
                #pragma unroll
                for (int mtl = 0; mtl < 4; ++mtl) {
                    U16 A0, A1; A0.u = W2f[mtl][0]; A1.u = W2f[mtl][1];
                    floatx4 acc = {0.f, 0.f, 0.f, 0.f};
                    acc = MFMA(A0.s, ub0.s, acc);
                    acc = MFMA(A1.s, ub1.s, acc);
                    U8b Bf3, Af3;
                    Bf3.u[0] = pk2(fmaxf(acc[0] + b2_s[mtl*16 + qd*4 + 0], 0.f),
                                   fmaxf(acc[1] + b2_s[mtl*16 + qd*4 + 1], 0.f));
                    Bf3.u[1] = pk2(fmaxf(acc[2] + b2_s[mtl*16 + qd*4 + 2], 0.f),
                                   fmaxf(acc[3] + b2_s[mtl*16 + qd*4 + 3], 0.f));
                    Af3.u[0] = W3h[mtl][0]; Af3.u[1] = W3h[mtl][1];
                    a3 = MFMA16(Af3.s, Bf3.s, a3);
                }
                float* sp = Sm + ((ig * 16 + n) * 18 + j) * 17 + qd * 4;
                #pragma unroll
                for (int r = 0; r < 4; ++r) sp[r] = a3[r] + b3_s[qd * 4 + r] + sp[r];
            };
            mlp1(w);
            mlp1(w + 8);
            mlp1(w + 16);
            mlp1(w + 24);
            if (w < 4) mlp1(32 + w);
        }
        // (c) soft(t-2) reads S[(t-2)%3]
        if (t >= 2) soft_acc(t - 2, Sbuf + ((t - 2) % 3) * 9792);
        __syncthreads();
    }

    // ---- reduce wAcc over 32 il-slots -> wA_s[h][j]; conv_w sum ----
    // wred sits in S1 region; last soft read S0 (chunk 9, 9%3=0).
    #pragma unroll
    for (int j = 0; j < 18; ++j) wred[tid * 18 + j] = wAcc[j];
    {
        float v = 0.f;
        for (int u = tid; u < 312; u += 512) v += conv_w[u];
        for (int d = 32; d > 0; d >>= 1) v += __shfl_down(v, d, 64);
        if (lane == 0) redb[w] = v;
    }
    __syncthreads();
    for (int u = tid; u < 288; u += 512) {
        const int h = u / 18, j = u - h * 18;
        float s = 0.f;
        #pragma unroll
        for (int sl = 0; sl < 32; ++sl) s += wred[(sl * 16 + h) * 18 + j];
        wA_s[u] = s;
    }
    __syncthreads();

    // ---- m[c] = sum_j wA[h][j] * v[c][j] ----
    if (tid < 256) {
        const int hb = (tid >> 4) * 18;
        float acc = 0.f;
        #pragma unroll
        for (int j = 0; j < 18; ++j) acc += wA_s[hb + j] * bf2f(v_sb[tid * 20 + j]);
        m_s[tid] = acc;
    }
    __syncthreads();

    float Ssum = 0.f;
    #pragma unroll
    for (int i = 0; i < 8; ++i) Ssum += redb[i];

    // ---- pooled = w_out . m  (8 waves x 32 rows, coalesced float4) ----
    {
        const float4 mm = *(const float4*)(m_s + lane * 4);
        for (int ol = 0; ol < 32; ++ol) {
            const int o = w * 32 + ol;
            const float4 wq = *(const float4*)(w_out + o * 256 + lane * 4);
            float d = wq.x * mm.x + wq.y * mm.y + wq.z * mm.z + wq.w * mm.w;
            for (int dd = 32; dd > 0; dd >>= 1) d += __shfl_down(d, dd, 64);
            if (lane == 0) pooled_s[o] = d;
        }
    }
    __syncthreads();

    // ---- residual + LayerNorm (first 4 waves) ----
    if (tid < 256) {
        const float y = pooled_s[tid] + b_out[tid] * Ssum + conv_b[0] + qf_s[tid];
        float s1 = y, s2 = y * y;
        for (int d = 32; d > 0; d >>= 1) { s1 += __shfl_down(s1, d, 64); s2 += __shfl_down(s2, d, 64); }
        if (lane == 0) { redb[16 + w] = s1; redb[20 + w] = s2; }
    }
    __syncthreads();
    if (tid < 256) {
        const float y = pooled_s[tid] + b_out[tid] * Ssum + conv_b[0] + qf_s[tid];
        const float S1 = redb[16] + redb[17] + redb[18] + redb[19];
        const float S2 = redb[20] + redb[21] + redb[22] + redb[23];
        const float mu = S1 * (1.0f / 256.0f);
        const float var = S2 * (1.0f / 256.0f) - mu * mu;
        out[b * 256 + tid] = (y - mu) * rsqrtf(var + 1e-5f) * ln_g[tid] + ln_b[tid];
    }
}

// ===========================================================================
extern "C" void kernel_launch(void* const* d_in, const int* in_sizes, int n_in,
                              void* d_out, int out_size, void* d_ws, size_t ws_size,
                              hipStream_t stream) {
    const float* x       = (const float*)d_in[0];
    const float* q       = (const float*)d_in[1];
    const float* w_dw    = (const float*)d_in[2];
    const float* b_dwp   = (const float*)d_in[3];
    const float* w_pw    = (const float*)d_in[4];
    const float* wk      = (const float*)d_in[5];
    const float* wv      = (const float*)d_in[6];
    const float* w_out   = (const float*)d_in[7];
    const float* b_out   = (const float*)d_in[8];
    const float* cw1     = (const float*)d_in[9];
    const float* cb1     = (const float*)d_in[10];
    const float* cw2     = (const float*)d_in[11];
    const float* cb2     = (const float*)d_in[12];
    const float* cw3     = (const float*)d_in[13];
    const float* cb3     = (const float*)d_in[14];
    const float* conv_w  = (const float*)d_in[15];
    const float* conv_b  = (const float*)d_in[16];
    const float* ln_g    = (const float*)d_in[17];
    const float* ln_b    = (const float*)d_in[18];
    float* out = (float*)d_out;

    k_all<<<256, 512, 0, stream>>>(x, q, w_dw, b_dwp, w_pw, wk, wv, w_out, b_out,
                                   cw1, cb1, cw2, cb2, cw3, cb3,
                                   conv_w, conv_b, ln_g, ln_b, out);
}

// Round 10
// 248.477 us; speedup vs baseline: 2.0178x; 1.0149x over previous
//
#include <hip/hip_runtime.h>
#include <hip/hip_bf16.h>
#include <math.h>

// ---------------------------------------------------------------------------
// DIM=256 HEADS=16 DHEAD=16 H=12 W=26 (HW=312)  Hk=3 Wk=6 (J=18)  B=256
// q_map[b,c,s] = q[b,(c*56+s)&255]
// Round 17: r16 + three chain-shortening edits (latency-bound at fixed
// 2 waves/SIMD; r16 validated MFMA16 fragment layout end-to-end):
//  1. sim via MFMA16 (16x16x16bf16_1k): DHEAD=16 is a K=16 problem; the
//     old K=32 MFMA used only qd<2 lanes with 8 serial ds_read_u16 each.
//     Now all 64 lanes gather 4 each -> worst-lane chain halves, no
//     divergence; BkU frags 16->8 regs.
//  2. GEMM3 dual accumulator (a3a/a3b): the 4-deep dependent MFMA16
//     chain (~100cy serial per mlp1 x45/wave) halves.
//  3. soft_acc: pairwise-tree max (depth 17->5) + 2-way partial sums.
// Everything else identical to r16 (passed, absmax 0.015625, dur 131us).
// ---------------------------------------------------------------------------

typedef __attribute__((ext_vector_type(8))) short short8;   // 8 bf16
typedef __attribute__((ext_vector_type(4))) short s4bf;     // 4 bf16
typedef __attribute__((ext_vector_type(4))) float floatx4;

union U16 { uint4 u; short8 s; };
union U8b { unsigned int u[2]; s4bf s; };

#define MFMA(A, B, C) __builtin_amdgcn_mfma_f32_16x16x32_bf16((A), (B), (C), 0, 0, 0)
#define MFMA16(A, B, C) __builtin_amdgcn_mfma_f32_16x16x16bf16_1k((A), (B), (C), 0, 0, 0)

__device__ __forceinline__ unsigned int f2bf(float f) {   // RNE f32->bf16 (low 16)
    unsigned int u = __float_as_uint(f);
    u += 0x7fffu + ((u >> 16) & 1u);
    return u >> 16;
}
__device__ __forceinline__ unsigned int pk2(float a, float b) {   // HW cvt_pk
    __hip_bfloat162 h = __float22bfloat162_rn(make_float2(a, b));
    union { __hip_bfloat162 h; unsigned int u; } cv; cv.h = h;
    return cv.u;
}
__device__ __forceinline__ float bf2f(unsigned short v) {
    return __uint_as_float((unsigned int)v << 16);
}
__device__ __forceinline__ uint4 pack8(float4 a, float4 b) {
    uint4 r;
    r.x = pk2(a.x, a.y); r.y = pk2(a.z, a.w);
    r.z = pk2(b.x, b.y); r.w = pk2(b.z, b.w);
    return r;
}

// ===========================================================================
__global__ __launch_bounds__(512, 2) void k_all(
    const float* __restrict__ x, const float* __restrict__ q,
    const float* __restrict__ w_dw, const float* __restrict__ b_dw,
    const float* __restrict__ w_pw,
    const float* __restrict__ wk, const float* __restrict__ wv,
    const float* __restrict__ w_out, const float* __restrict__ b_out,
    const float* __restrict__ cw1, const float* __restrict__ cb1,
    const float* __restrict__ cw2, const float* __restrict__ cb2,
    const float* __restrict__ cw3, const float* __restrict__ cb3,
    const float* __restrict__ conv_w, const float* __restrict__ conv_b,
    const float* __restrict__ ln_g, const float* __restrict__ ln_b,
    float* __restrict__ out)
{
    const int b = blockIdx.x, tid = threadIdx.x;
    const int w = tid >> 6, lane = tid & 63;
    const int n = lane & 15, qd = lane >> 4;

    // ---- persistent LDS (~20.9 KB) ----
    __shared__ float qf_s[256];
    __shared__ unsigned short q_sb[256];            // bf16(q*0.25)
    __shared__ unsigned short v_sb[5120];           // v bf16 [256][20]
    __shared__ float F0[468], F1[216];              // log tables [26][18], [12][18]
    __shared__ unsigned int lutxy[312];             // ix | iy<<16
    __shared__ float off_s[36], n0_s[18], n1_s[18];
    __shared__ float sx0[18], sy0[18], swx[18], swy[18];
    __shared__ float b2_s[64], b3_s[16];
    __shared__ __align__(16) float w1p[4][8][8];    // [qd][kp][6 used]
    __shared__ float wA_s[288];
    __shared__ __align__(16) float m_s[256];
    __shared__ float pooled_s[256], redb[24];
    // ---- union region (117504 B): S triple buffer, 3 x [32][18][17] f32 ----
    __shared__ __align__(16) unsigned char UB[117504];
    float* Sbuf = (float*)UB;
    unsigned short* kvT = (unsigned short*)UB;       // [18 j][264 c] bf16 9504B
    float* qsw = (float*)UB;                         // 16 copies x 258 = 16512B
    float* t_s = (float*)(UB + 16512);               // [18 p][256 c] 18432B
    unsigned short* k_sb = (unsigned short*)(UB + 16512);  // k bf16 [256][20]
    float* wred = (float*)(UB + 39168);              // S1 region: 512x18 f32

    // ---- stage 0 ----
    if (tid < 256) {
        const float qv = q[b * 256 + tid];
        qf_s[tid] = qv;
        q_sb[tid] = (unsigned short)f2bf(qv * 0.25f);
    }
    for (int u = tid; u < 4128; u += 512) {
        const int r = u / 258, i = u - r * 258;
        qsw[u] = (i < 256) ? q[b * 256 + i] : 0.f;
    }
    if (tid < 312) {
        const int iy = tid / 26;
        lutxy[tid] = (unsigned int)(tid - iy * 26) | ((unsigned int)iy << 16);
    }
    if (tid < 64) b2_s[tid] = cb2[tid];
    if (tid < 16) b3_s[tid] = cb3[tid];
    if (tid >= 64 && tid < 96) {                     // CPB layer-1 weight table
        const int t2 = tid - 64;
        const int qdi = t2 >> 3, kp = t2 & 7;
        const int kk0 = 2 * kp, kk1 = 2 * kp + 1;
        const int kid0 = (kk0 < 8) ? (qdi * 8 + kk0) : (32 + qdi * 8 + kk0 - 8);
        const int kid1 = (kk1 < 8) ? (qdi * 8 + kk1) : (32 + qdi * 8 + kk1 - 8);
        w1p[qdi][kp][0] = cw1[kid0 * 2];
        w1p[qdi][kp][1] = cw1[kid0 * 2 + 1];
        w1p[qdi][kp][2] = cb1[kid0];
        w1p[qdi][kp][3] = cw1[kid1 * 2];
        w1p[qdi][kp][4] = cw1[kid1 * 2 + 1];
        w1p[qdi][kp][5] = cb1[kid1];
    }
    __syncthreads();

    // ---- depthwise conv 6x6 s4 p1 + GELU -> t_s ----
    {
        const int c = tid & 255, g = tid >> 8;     // g: jw-half
        float wreg[36];
        const float4* wdw4 = (const float4*)w_dw;  // [c][36] contiguous
        #pragma unroll
        for (int i = 0; i < 9; ++i) {
            const float4 t4 = wdw4[c * 9 + i];
            wreg[i * 4 + 0] = t4.x; wreg[i * 4 + 1] = t4.y;
            wreg[i * 4 + 2] = t4.z; wreg[i * 4 + 3] = t4.w;
        }
        float acc[9];
        const float bv = b_dw[c];
        #pragma unroll
        for (int a = 0; a < 9; ++a) acc[a] = bv;
        const int cb = (c * 56) & 255;
        const int cp = (c & 15) * 258;
        for (int jh = 0; jh < 3; ++jh) {
            for (int kh = 0; kh < 6; ++kh) {
                const int ih = jh * 4 - 1 + kh;
                if (ih < 0 || ih >= 12) continue;
                const int rb = ih * 26;
                #pragma unroll
                for (int jwl = 0; jwl < 3; ++jwl) {
                    const int jw = g * 3 + jwl;
                    #pragma unroll
                    for (int kw = 0; kw < 6; ++kw) {
                        const int iw = jw * 4 - 1 + kw;
                        if (iw < 0 || iw >= 26) continue;
                        acc[jh * 3 + jwl] += wreg[kh * 6 + kw] * qsw[cp + ((cb + rb + iw) & 255)];
                    }
                }
            }
        }
        #pragma unroll
        for (int a = 0; a < 9; ++a) {
            const int jh = a / 3, jwl = a - jh * 3;
            const int p = jh * 6 + g * 3 + jwl;
            const float v = acc[a];
            t_s[p * 256 + c] = 0.5f * v * (1.0f + erff(v * 0.70710678118654752f));
        }
    }
    __syncthreads();

    // ---- offsets: 36 dots over 256 channels ----
    for (int oi = w; oi < 36; oi += 8) {
        const int o = oi / 18, p = oi - o * 18;
        float s = 0.f;
        for (int c = lane; c < 256; c += 64) s += w_pw[o * 256 + c] * t_s[p * 256 + c];
        for (int d = 32; d > 0; d >>= 1) s += __shfl_down(s, d, 64);
        if (lane == 0) off_s[oi] = 4.0f * tanhf(s);
    }
    __syncthreads();

    // ---- grid coords + bilinear params ----
    if (tid < 18) {
        const int j = tid, jh = j / 6, jw = j - jh * 6;
        const float vg0 = (float)jw + off_s[j];
        const float vg1 = (float)jh + off_s[18 + j];
        const float n0 = 2.0f * vg0 / 2.0f - 1.0f;
        const float n1 = 2.0f * vg1 / 5.0f - 1.0f;
        n0_s[j] = n0; n1_s[j] = n1;
        const float xp = ((n0 + 1.0f) * 26.0f - 1.0f) * 0.5f;
        const float yp = ((n1 + 1.0f) * 12.0f - 1.0f) * 0.5f;
        const float x0 = floorf(xp), y0 = floorf(yp);
        sx0[j] = x0; sy0[j] = y0; swx[j] = xp - x0; swy[j] = yp - y0;
    }
    __syncthreads();

    // ---- bilinear sample -> kvT bf16 [j][264]; F0/F1 log tables ----
    {
        const int c = tid & 255, g = tid >> 8;
        const float* xb = x + ((size_t)b * 256 + c) * 312;
        for (int jj = 0; jj < 9; ++jj) {
            const int j = g * 9 + jj;
            const int x0 = (int)sx0[j], y0 = (int)sy0[j];
            const int x1 = x0 + 1, y1 = y0 + 1;
            const float wx1 = swx[j], wy1 = swy[j];
            const float wx0 = 1.f - wx1, wy0 = 1.f - wy1;
            const bool xv0 = (x0 >= 0) & (x0 < 26), xv1 = (x1 >= 0) & (x1 < 26);
            const bool yv0 = (y0 >= 0) & (y0 < 12), yv1 = (y1 >= 0) & (y1 < 12);
            const float v00 = (xv0 & yv0) ? xb[y0 * 26 + x0] : 0.f;
            const float v01 = (xv1 & yv0) ? xb[y0 * 26 + x1] : 0.f;
            const float v10 = (xv0 & yv1) ? xb[y1 * 26 + x0] : 0.f;
            const float v11 = (xv1 & yv1) ? xb[y1 * 26 + x1] : 0.f;
            const float val = wy0 * (wx0 * v00 + wx1 * v01) + wy1 * (wx0 * v10 + wx1 * v11);
            kvT[j * 264 + c] = (unsigned short)f2bf(val);
        }
    }
    for (int u = tid; u < 684; u += 512) {
        if (u < 468) {
            const int ixv = u / 18, j = u - ixv * 18;
            const float p0 = (float)ixv * (2.0f / 11.0f) - 1.0f - n0_s[j];
            F0[u] = copysignf(__logf(1.0f + fabsf(p0)), p0);
        } else {
            const int u2 = u - 468;
            const int iyv = u2 / 18, j = u2 - iyv * 18;
            const float p1 = (float)iyv * (2.0f / 25.0f) - 1.0f - n1_s[j];
            F1[u2] = copysignf(__logf(1.0f + fabsf(p1)), p1);
        }
    }
    __syncthreads();

    // ---- k/v projection via MFMA: wave w -> matrix (w&1), mtb = w>>1 ----
    {
        const int m2 = w & 1, mtb = w >> 1;
        const float4* wm4 = (const float4*)(m2 ? wv : wk);
        floatx4 pa[4][2];
        #pragma unroll
        for (int a = 0; a < 4; ++a) {
            pa[a][0] = (floatx4){0.f, 0.f, 0.f, 0.f};
            pa[a][1] = (floatx4){0.f, 0.f, 0.f, 0.f};
        }
        #pragma unroll 2
        for (int ks = 0; ks < 8; ++ks) {
            U16 b0, b1;
            b0.u = *(const uint4*)(kvT + n * 264 + ks * 32 + qd * 8);
            b1.u = make_uint4(0u, 0u, 0u, 0u);
            if (n < 2) b1.u = *(const uint4*)(kvT + (16 + n) * 264 + ks * 32 + qd * 8);
            #pragma unroll
            for (int mtl = 0; mtl < 4; ++mtl) {
                const int mt = mtb + mtl * 4;
                const int f4i = (mt * 16 + n) * 64 + ks * 8 + qd * 2;
                U16 A; A.u = pack8(wm4[f4i], wm4[f4i + 1]);
                pa[mtl][0] = MFMA(A.s, b0.s, pa[mtl][0]);
                pa[mtl][1] = MFMA(A.s, b1.s, pa[mtl][1]);
            }
        }
        unsigned short* dst = m2 ? v_sb : k_sb;
        #pragma unroll
        for (int mtl = 0; mtl < 4; ++mtl) {
            const int mt = mtb + mtl * 4;
            #pragma unroll
            for (int r = 0; r < 4; ++r) {
                const int o = mt * 16 + qd * 4 + r;
                dst[o * 20 + n] = (unsigned short)f2bf(pa[mtl][0][r]);
                if (n < 2) dst[o * 20 + 16 + n] = (unsigned short)f2bf(pa[mtl][1][r]);
            }
        }
    }
    __syncthreads();

    // ---- per-lane weight fragments (late load) ----
    uint4 W2f[4][2];
    unsigned int W3h[4][2];                          // K=16 A-frags for GEMM3
    {
        const float4* cw2_4 = (const float4*)cw2;
        #pragma unroll
        for (int mtl = 0; mtl < 4; ++mtl)
            #pragma unroll
            for (int ks = 0; ks < 2; ++ks) {
                const int base = (mtl * 16 + n) * 16 + ks * 8 + qd * 2;
                W2f[mtl][ks] = pack8(cw2_4[base], cw2_4[base + 1]);
            }
        const float4* cw3_4 = (const float4*)cw3;
        #pragma unroll
        for (int kc = 0; kc < 4; ++kc) {
            const float4 v = cw3_4[n * 16 + kc * 4 + qd];  // cw3[n*64+kc*16+qd*4..]
            W3h[kc][0] = pk2(v.x, v.y);
            W3h[kc][1] = pk2(v.z, v.w);
        }
    }

    // ---- Bk fragments for sim via MFMA16: lane (n,qd) col j=jt*16+n, k=qd*4+e
    unsigned int Bk16[2][2][2];                      // [hh][jt][2 uints]
    #pragma unroll
    for (int hh = 0; hh < 2; ++hh)
        #pragma unroll
        for (int jt = 0; jt < 2; ++jt) {
            unsigned int u0 = 0, u1 = 0;
            const int j = jt * 16 + n;
            if (j < 18) {
                const int h = w * 2 + hh;
                const int cb0 = (h * 16 + qd * 4) * 20 + j;
                u0 = (unsigned)k_sb[cb0]      | ((unsigned)k_sb[cb0 + 20] << 16);
                u1 = (unsigned)k_sb[cb0 + 40] | ((unsigned)k_sb[cb0 + 60] << 16);
            }
            Bk16[hh][jt][0] = u0; Bk16[hh][jt][1] = u1;
        }
    // A-gather base constants: ((h*16+qd*4)*56) & 255 per hh
    int kA[2];
    #pragma unroll
    for (int hh = 0; hh < 2; ++hh)
        kA[hh] = (((w * 2 + hh) * 16 + qd * 4) * 56) & 255;
    __syncthreads();   // k_sb dead; S triple buffer live from here

    // ---- 3-stage pipelined chunk loop: 12 intervals, 1 barrier each ----
    float wAcc[18];
    #pragma unroll
    for (int j = 0; j < 18; ++j) wAcc[j] = 0.f;

    auto soft_acc = [&](int chp, const float* Sp) {
        const int il = tid >> 4, h = tid & 15;
        const int CIp = (chp == 9) ? 24 : 32;
        if (il < CIp) {
            const float cwv = conv_w[chp * 32 + il];
            float lv[18];
            const float* row = Sp + (il * 18) * 17 + h;
            #pragma unroll
            for (int j = 0; j < 18; ++j) lv[j] = row[j * 17];
            // pairwise-tree max (depth ~5 vs 17)
            float mx[9];
            #pragma unroll
            for (int p = 0; p < 9; ++p) mx[p] = fmaxf(lv[2 * p], lv[2 * p + 1]);
            #pragma unroll
            for (int p = 0; p < 4; ++p) mx[p] = fmaxf(mx[p], mx[p + 4]);
            mx[0] = fmaxf(mx[0], mx[2]); mx[1] = fmaxf(mx[1], mx[3]);
            const float m = fmaxf(fmaxf(mx[0], mx[1]), mx[8]);
            // exp + 2-way partial sums (chain 9 vs 18)
            float sa = 0.f, sb = 0.f;
            #pragma unroll
            for (int j = 0; j < 18; j += 2) {
                lv[j] = __expf(lv[j] - m);     sa += lv[j];
                lv[j + 1] = __expf(lv[j + 1] - m); sb += lv[j + 1];
            }
            const float wgt = cwv / (sa + sb);
            #pragma unroll
            for (int j = 0; j < 18; ++j) wAcc[j] = fmaf(wgt, lv[j], wAcc[j]);
        }
    };

    for (int t = 0; t < 12; ++t) {
        // (a) sim(t) -> S[t%3]  — MFMA16, all lanes active, 4 gathers/lane
        if (t < 10) {
            float* Sc = Sbuf + (t % 3) * 9792;
            const int ibase = t * 32;
            #pragma unroll
            for (int hh = 0; hh < 2; ++hh) {
                const int h = w * 2 + hh;
                const int ka = kA[hh];
                #pragma unroll
                for (int ig = 0; ig < 2; ++ig) {
                    const int ii = ibase + ig * 16 + n;
                    const unsigned int a0 =
                        (unsigned)q_sb[(ka + ii) & 255] |
                        ((unsigned)q_sb[(ka + 56 + ii) & 255] << 16);
                    const unsigned int a1 =
                        (unsigned)q_sb[(ka + 112 + ii) & 255] |
                        ((unsigned)q_sb[(ka + 168 + ii) & 255] << 16);
                    U8b Af; Af.u[0] = a0; Af.u[1] = a1;
                    #pragma unroll
                    for (int jt = 0; jt < 2; ++jt) {
                        U8b Bf; Bf.u[0] = Bk16[hh][jt][0]; Bf.u[1] = Bk16[hh][jt][1];
                        floatx4 D = {0.f, 0.f, 0.f, 0.f};
                        D = MFMA16(Af.s, Bf.s, D);
                        const int j = jt * 16 + n;
                        if (j < 18) {
                            #pragma unroll
                            for (int r = 0; r < 4; ++r)
                                Sc[((ig * 16 + qd * 4 + r) * 18 + j) * 17 + h] = D[r];
                        }
                    }
                }
            }
        }
        // (b) mlp(t-1) RMW S[(t-1)%3] — GEMM2->GEMM3 fused, dual a3 chain
        if (t >= 1 && t < 11) {
            const int chm = t - 1;
            float* Sm = Sbuf + (chm % 3) * 9792;
            const int ibase = chm * 32;
            auto mlp1 = [&](int tt) {
                const int ig = (tt >= 18) ? 1 : 0;
                const int j = tt - ig * 18;
                const int i0 = ibase + ig * 16 + n;
                const unsigned int lv2 = lutxy[(i0 < 312) ? i0 : 311];
                const int ix = (int)(lv2 & 0xffffu), iy = (int)(lv2 >> 16);
                const float f0 = F0[ix * 18 + j];
                const float f1 = F1[iy * 18 + j];
                U16 ub0, ub1;
                {
                    unsigned int uu[8];
                    #pragma unroll
                    for (int kp = 0; kp < 8; ++kp) {
                        const float* wp = &w1p[qd][kp][0];
                        const float ha = fmaxf(fmaf(wp[0], f0, fmaf(wp[1], f1, wp[2])), 0.f);
                        const float hb = fmaxf(fmaf(wp[3], f0, fmaf(wp[4], f1, wp[5])), 0.f);
                        uu[kp] = pk2(ha, hb);
                    }
                    ub0.u = make_uint4(uu[0], uu[1], uu[2], uu[3]);
                    ub1.u = make_uint4(uu[4], uu[5], uu[6], uu[7]);
                }
                // GEMM2 (K=32) -> relu -> pack -> GEMM3 partial (K=16), fused
                floatx4 a3a = {0.f, 0.f, 0.f, 0.f};
                floatx4 a3b = {0.f, 0.f, 0.f, 0.f};
                #pragma unroll
                for (int mtl = 0; mtl < 4; ++mtl) {
                    U16 A0, A1; A0.u = W2f[mtl][0]; A1.u = W2f[mtl][1];
                    floatx4 acc = {0.f, 0.f, 0.f, 0.f};
                    acc = MFMA(A0.s, ub0.s, acc);
                    acc = MFMA(A1.s, ub1.s, acc);
                    U8b Bf3, Af3;
                    Bf3.u[0] = pk2(fmaxf(acc[0] + b2_s[mtl*16 + qd*4 + 0], 0.f),
                                   fmaxf(acc[1] + b2_s[mtl*16 + qd*4 + 1], 0.f));
                    Bf3.u[1] = pk2(fmaxf(acc[2] + b2_s[mtl*16 + qd*4 + 2], 0.f),
                                   fmaxf(acc[3] + b2_s[mtl*16 + qd*4 + 3], 0.f));
                    Af3.u[0] = W3h[mtl][0]; Af3.u[1] = W3h[mtl][1];
                    if (mtl & 1) a3b = MFMA16(Af3.s, Bf3.s, a3b);
                    else         a3a = MFMA16(Af3.s, Bf3.s, a3a);
                }
                float* sp = Sm + ((ig * 16 + n) * 18 + j) * 17 + qd * 4;
                #pragma unroll
                for (int r = 0; r < 4; ++r)
                    sp[r] = a3a[r] + a3b[r] + b3_s[qd * 4 + r] + sp[r];
            };
            mlp1(w);
            mlp1(w + 8);
            mlp1(w + 16);
            mlp1(w + 24);
            if (w < 4) mlp1(32 + w);
        }
        // (c) soft(t-2) reads S[(t-2)%3]
        if (t >= 2) soft_acc(t - 2, Sbuf + ((t - 2) % 3) * 9792);
        __syncthreads();
    }

    // ---- reduce wAcc over 32 il-slots -> wA_s[h][j]; conv_w sum ----
    // wred sits in S1 region; last soft read S0 (chunk 9, 9%3=0).
    #pragma unroll
    for (int j = 0; j < 18; ++j) wred[tid * 18 + j] = wAcc[j];
    {
        float v = 0.f;
        for (int u = tid; u < 312; u += 512) v += conv_w[u];
        for (int d = 32; d > 0; d >>= 1) v += __shfl_down(v, d, 64);
        if (lane == 0) redb[w] = v;
    }
    __syncthreads();
    for (int u = tid; u < 288; u += 512) {
        const int h = u / 18, j = u - h * 18;
        float s = 0.f;
        #pragma unroll
        for (int sl = 0; sl < 32; ++sl) s += wred[(sl * 16 + h) * 18 + j];
        wA_s[u] = s;
    }
    __syncthreads();

    // ---- m[c] = sum_j wA[h][j] * v[c][j] ----
    if (tid < 256) {
        const int hb = (tid >> 4) * 18;
        float acc = 0.f;
        #pragma unroll
        for (int j = 0; j < 18; ++j) acc += wA_s[hb + j] * bf2f(v_sb[tid * 20 + j]);
        m_s[tid] = acc;
    }
    __syncthreads();

    float Ssum = 0.f;
    #pragma unroll
    for (int i = 0; i < 8; ++i) Ssum += redb[i];

    // ---- pooled = w_out . m  (8 waves x 32 rows, coalesced float4) ----
    {
        const float4 mm = *(const float4*)(m_s + lane * 4);
        for (int ol = 0; ol < 32; ++ol) {
            const int o = w * 32 + ol;
            const float4 wq = *(const float4*)(w_out + o * 256 + lane * 4);
            float d = wq.x * mm.x + wq.y * mm.y + wq.z * mm.z + wq.w * mm.w;
            for (int dd = 32; dd > 0; dd >>= 1) d += __shfl_down(d, dd, 64);
            if (lane == 0) pooled_s[o] = d;
        }
    }
    __syncthreads();

    // ---- residual + LayerNorm (first 4 waves) ----
    if (tid < 256) {
        const float y = pooled_s[tid] + b_out[tid] * Ssum + conv_b[0] + qf_s[tid];
        float s1 = y, s2 = y * y;
        for (int d = 32; d > 0; d >>= 1) { s1 += __shfl_down(s1, d, 64); s2 += __shfl_down(s2, d, 64); }
        if (lane == 0) { redb[16 + w] = s1; redb[20 + w] = s2; }
    }
    __syncthreads();
    if (tid < 256) {
        const float y = pooled_s[tid] + b_out[tid] * Ssum + conv_b[0] + qf_s[tid];
        const float S1 = redb[16] + redb[17] + redb[18] + redb[19];
        const float S2 = redb[20] + redb[21] + redb[22] + redb[23];
        const float mu = S1 * (1.0f / 256.0f);
        const float var = S2 * (1.0f / 256.0f) - mu * mu;
        out[b * 256 + tid] = (y - mu) * rsqrtf(var + 1e-5f) * ln_g[tid] + ln_b[tid];
    }
}

// ===========================================================================
extern "C" void kernel_launch(void* const* d_in, const int* in_sizes, int n_in,
                              void* d_out, int out_size, void* d_ws, size_t ws_size,
                              hipStream_t stream) {
    const float* x       = (const float*)d_in[0];
    const float* q       = (const float*)d_in[1];
    const float* w_dw    = (const float*)d_in[2];
    const float* b_dwp   = (const float*)d_in[3];
    const float* w_pw    = (const float*)d_in[4];
    const float* wk      = (const float*)d_in[5];
    const float* wv      = (const float*)d_in[6];
    const float* w_out   = (const float*)d_in[7];
    const float* b_out   = (const float*)d_in[8];
    const float* cw1     = (const float*)d_in[9];
    const float* cb1     = (const float*)d_in[10];
    const float* cw2     = (const float*)d_in[11];
    const float* cb2     = (const float*)d_in[12];
    const float* cw3     = (const float*)d_in[13];
    const float* cb3     = (const float*)d_in[14];
    const float* conv_w  = (const float*)d_in[15];
    const float* conv_b  = (const float*)d_in[16];
    const float* ln_g    = (const float*)d_in[17];
    const float* ln_b    = (const float*)d_in[18];
    float* out = (float*)d_out;

    k_all<<<256, 512, 0, stream>>>(x, q, w_dw, b_dwp, w_pw, wk, wv, w_out, b_out,
                                   cw1, cb1, cw2, cb2, cw3, cb3,
                                   conv_w, conv_b, ln_g, ln_b, out);
}